// Round 1
// baseline (1026.625 us; speedup 1.0000x reference)
//
#include <hip/hip_runtime.h>
#include <hip/hip_bf16.h>

typedef __bf16 bf16;
typedef __bf16 bf16x8 __attribute__((ext_vector_type(8)));
typedef float f32x4 __attribute__((ext_vector_type(4)));

__device__ __forceinline__ void gld16(const void* g, void* l) {
  __builtin_amdgcn_global_load_lds((const __attribute__((address_space(1))) void*)g,
                                   (__attribute__((address_space(3))) void*)l, 16, 0, 0);
}

// ---------------- weight fp32 -> bf16 convert ----------------
__global__ void cvt_weights(const float* __restrict__ wq, const float* __restrict__ wkv,
                            const float* __restrict__ wp, const float* __restrict__ w1,
                            const float* __restrict__ w2,
                            bf16* __restrict__ wqkv, bf16* __restrict__ wpb,
                            bf16* __restrict__ w1b, bf16* __restrict__ w2b) {
  int i = blockIdx.x * 256 + threadIdx.x;
  if (i < 65536) wqkv[i] = (bf16)wq[i];
  else if (i < 131072) wqkv[i] = (bf16)wkv[i - 65536];
  else if (i < 196608) wpb[i - 131072] = (bf16)wp[i - 131072];
  else if (i < 458752) w1b[i - 196608] = (bf16)w1[i - 196608];
  else if (i < 720896) w2b[i - 458752] = (bf16)w2[i - 458752];
}

// ---------------- LayerNorm (wave per row, rows of 256) ----------------
__launch_bounds__(256)
__global__ void ln_kernel(const float* __restrict__ x, const float* __restrict__ g,
                          const float* __restrict__ b, bf16* __restrict__ out) {
  const int row = blockIdx.x * 4 + (threadIdx.x >> 6);
  const int lane = threadIdx.x & 63;
  const float4 v = ((const float4*)(x + (long)row * 256))[lane];
  float s = v.x + v.y + v.z + v.w;
#pragma unroll
  for (int o = 1; o < 64; o <<= 1) s += __shfl_xor(s, o);
  const float mu = s * (1.f / 256.f);
  const float dx = v.x - mu, dy = v.y - mu, dz = v.z - mu, dw = v.w - mu;
  float q = dx * dx + dy * dy + dz * dz + dw * dw;
#pragma unroll
  for (int o = 1; o < 64; o <<= 1) q += __shfl_xor(q, o);
  const float rstd = rsqrtf(q * (1.f / 256.f) + 1e-5f);
  const float4 gg = ((const float4*)g)[lane];
  const float4 bb = ((const float4*)b)[lane];
  union { bf16 h[4]; uint2 u; } pk;
  pk.h[0] = (bf16)(dx * rstd * gg.x + bb.x);
  pk.h[1] = (bf16)(dy * rstd * gg.y + bb.y);
  pk.h[2] = (bf16)(dz * rstd * gg.z + bb.z);
  pk.h[3] = (bf16)(dw * rstd * gg.w + bb.w);
  *(uint2*)(out + (long)row * 256 + lane * 4) = pk.u;
}

// ---------------- bf16 MFMA GEMM: C[M x Nn] = A[M x K] @ B[Nn x K]^T ----------------
// EPI 0: store bf16. EPI 1: f32 store of acc + bias[col] + res[idx]. EPI 2: bf16 store of gelu(acc+bias).
template <int EPI>
__launch_bounds__(256)
__global__ void gemm_kernel(const bf16* __restrict__ A, const bf16* __restrict__ B,
                            void* C, const float* __restrict__ bias,
                            const float* res, int Nn, int K) {
  __shared__ bf16 Alds[128 * 64];
  __shared__ bf16 Blds[128 * 64];
  const int tid = threadIdx.x;
  const int w = tid >> 6, lane = tid & 63;
  const int wr = w >> 1, wc = w & 1;
  const long m0 = (long)blockIdx.y * 128;
  const long n0 = (long)blockIdx.x * 128;
  const int srow = lane >> 3;
  const int scol = (lane & 7) * 8;
  f32x4 acc[4][4] = {};
  for (int kt = 0; kt < K; kt += 64) {
#pragma unroll
    for (int i = 0; i < 4; ++i) {
      const int c = w * 4 + i;
      const int row = c * 8 + srow;
      gld16(A + (m0 + row) * K + kt + scol, Alds + c * 512);
      gld16(B + (n0 + row) * K + kt + scol, Blds + c * 512);
    }
    asm volatile("s_waitcnt vmcnt(0)" ::: "memory");
    __syncthreads();
#pragma unroll
    for (int ks = 0; ks < 2; ++ks) {
      const int colo = ks * 32 + (lane >> 4) * 8;
      bf16x8 af[4], bfr[4];
#pragma unroll
      for (int fm = 0; fm < 4; ++fm)
        af[fm] = *(const bf16x8*)(Alds + (wr * 64 + fm * 16 + (lane & 15)) * 64 + colo);
#pragma unroll
      for (int fn = 0; fn < 4; ++fn)
        bfr[fn] = *(const bf16x8*)(Blds + (wc * 64 + fn * 16 + (lane & 15)) * 64 + colo);
#pragma unroll
      for (int fm = 0; fm < 4; ++fm)
#pragma unroll
        for (int fn = 0; fn < 4; ++fn)
          acc[fm][fn] = __builtin_amdgcn_mfma_f32_16x16x32_bf16(af[fm], bfr[fn], acc[fm][fn], 0, 0, 0);
    }
    __syncthreads();
  }
#pragma unroll
  for (int fm = 0; fm < 4; ++fm)
#pragma unroll
    for (int fn = 0; fn < 4; ++fn)
#pragma unroll
      for (int r = 0; r < 4; ++r) {
        const long row = m0 + wr * 64 + fm * 16 + (lane >> 4) * 4 + r;
        const long col = n0 + wc * 64 + fn * 16 + (lane & 15);
        const long idx = row * Nn + col;
        const float v = acc[fm][fn][r];
        if constexpr (EPI == 0) {
          ((bf16*)C)[idx] = (bf16)v;
        } else if constexpr (EPI == 1) {
          ((float*)C)[idx] = v + bias[col] + res[idx];
        } else {
          const float t = v + bias[col];
          ((bf16*)C)[idx] = (bf16)(0.5f * t * (1.f + erff(t * 0.70710678118654752f)));
        }
      }
}

// ---------------- local window attention (head 0), one block per (window, batch) ----------------
__launch_bounds__(256)
__global__ void lattn_kernel(const bf16* __restrict__ qkv, bf16* __restrict__ attn) {
  const int j = blockIdx.x, b = blockIdx.y;
  const int tid = threadIdx.x, w = tid >> 6, lane = tid & 63;
  __shared__ bf16 Qs[64 * 40];        // [row][d] stride 40
  __shared__ bf16 Ks[192 * 40];       // [c][d]   stride 40
  __shared__ bf16 Kt[32 * 200];       // [d][c]   stride 200
  __shared__ bf16 Ps[4][16 * 200];    // per-wave P [row16][c] stride 200
  const float scale = 0.17677669529663687f;  // 32^-0.5
  const long base = (long)b * 8192 + (long)j * 64;
  for (int i = tid; i < 64 * 32; i += 256) {
    const int r = i >> 5, d = i & 31;
    Qs[r * 40 + d] = (bf16)((float)qkv[(base + r) * 512 + d] * scale);
  }
  for (int i = tid; i < 192 * 32; i += 256) {
    const int c = i >> 5, d = i & 31;
    const long tc = (long)j * 64 - 64 + c;
    float kv = 0.f;
    if (tc >= 0 && tc < 8192) kv = (float)qkv[((long)b * 8192 + tc) * 512 + 256 + d];
    const bf16 kb = (bf16)kv;   // k == v (both from kv projection)
    Ks[c * 40 + d] = kb;
    Kt[d * 200 + c] = kb;
  }
  __syncthreads();
  const int l15 = lane & 15, l4 = lane >> 4;
  const bf16x8 aq = *(const bf16x8*)(Qs + (w * 16 + l15) * 40 + l4 * 8);
  const f32x4 zz = {0.f, 0.f, 0.f, 0.f};
  f32x4 S[12];
#pragma unroll
  for (int fn = 0; fn < 12; ++fn) {
    const bf16x8 bk = *(const bf16x8*)(Ks + (fn * 16 + l15) * 40 + l4 * 8);
    S[fn] = __builtin_amdgcn_mfma_f32_16x16x32_bf16(aq, bk, zz, 0, 0, 0);
  }
#pragma unroll
  for (int fn = 0; fn < 12; ++fn) {
    const long tc = (long)j * 64 - 64 + fn * 16 + l15;
    if (tc < 0 || tc >= 8192) { S[fn][0] = -1e9f; S[fn][1] = -1e9f; S[fn][2] = -1e9f; S[fn][3] = -1e9f; }
  }
  float sinv[4];
#pragma unroll
  for (int r = 0; r < 4; ++r) {
    float m = -1e30f;
#pragma unroll
    for (int fn = 0; fn < 12; ++fn) m = fmaxf(m, S[fn][r]);
#pragma unroll
    for (int o = 1; o < 16; o <<= 1) m = fmaxf(m, __shfl_xor(m, o));
    float s = 0.f;
#pragma unroll
    for (int fn = 0; fn < 12; ++fn) { const float e = __expf(S[fn][r] - m); S[fn][r] = e; s += e; }
#pragma unroll
    for (int o = 1; o < 16; o <<= 1) s += __shfl_xor(s, o);
    sinv[r] = 1.f / s;
  }
#pragma unroll
  for (int fn = 0; fn < 12; ++fn)
#pragma unroll
    for (int r = 0; r < 4; ++r)
      Ps[w][(l4 * 4 + r) * 200 + fn * 16 + l15] = (bf16)(S[fn][r] * sinv[r]);
  __syncthreads();
  f32x4 O[2] = {};
#pragma unroll
  for (int ks = 0; ks < 6; ++ks) {
    const bf16x8 ap = *(const bf16x8*)(Ps[w] + l15 * 200 + ks * 32 + l4 * 8);
#pragma unroll
    for (int fe = 0; fe < 2; ++fe) {
      const bf16x8 bv = *(const bf16x8*)(Kt + (fe * 16 + l15) * 200 + ks * 32 + l4 * 8);
      O[fe] = __builtin_amdgcn_mfma_f32_16x16x32_bf16(ap, bv, O[fe], 0, 0, 0);
    }
  }
#pragma unroll
  for (int fe = 0; fe < 2; ++fe)
#pragma unroll
    for (int r = 0; r < 4; ++r)
      attn[(base + w * 16 + l4 * 4 + r) * 256 + fe * 16 + l15] = (bf16)O[fe][r];
}

// ---------------- linear attn: per-(b,h,d) column max & 1/sumexp over N ----------------
__launch_bounds__(256)
__global__ void kstats_kernel(const bf16* __restrict__ qkv, float* __restrict__ Mx,
                              float* __restrict__ Sinv) {
  const int bh = blockIdx.x;
  const int b = bh / 7, h = bh % 7 + 1;
  const int tid = threadIdx.x;
  const int d = tid & 31, grp = tid >> 5;
  const bf16* kp = qkv + (long)b * 8192 * 512 + 256 + h * 32 + d;
  float m = -1e30f;
  for (int n = grp; n < 8192; n += 8) m = fmaxf(m, (float)kp[(long)n * 512]);
  __shared__ float red1[8][32];
  __shared__ float red2[8][32];
  red1[grp][d] = m;
  __syncthreads();
#pragma unroll
  for (int g2 = 0; g2 < 8; ++g2) m = fmaxf(m, red1[g2][d]);
  float s = 0.f;
  for (int n = grp; n < 8192; n += 8) s += __expf((float)kp[(long)n * 512] - m);
  red2[grp][d] = s;
  __syncthreads();
  if (grp == 0) {
#pragma unroll
    for (int g2 = 1; g2 < 8; ++g2) s += red2[g2][d];
    Mx[bh * 32 + d] = m;
    Sinv[bh * 32 + d] = 1.f / s;
  }
}

// ---------------- linear attn: ctx[d][e] += sum_n exp(k[n,d]-M[d]) * k[n,e] ----------------
__launch_bounds__(256)
__global__ void ctx_kernel(const bf16* __restrict__ qkv, const float* __restrict__ Mx,
                           float* __restrict__ ctx) {
  const int bh = blockIdx.x;
  const int b = bh / 7, h = bh % 7 + 1;
  const int w = threadIdx.x >> 6, lane = threadIdx.x & 63;
  const int e = lane & 31, half = lane >> 5;
  const float Md = Mx[bh * 32 + e];
  float acc[32];
#pragma unroll
  for (int d = 0; d < 32; ++d) acc[d] = 0.f;
  const long tok0 = (long)blockIdx.y * 512 + w * 128 + half;
  const bf16* kp = qkv + ((long)b * 8192 + tok0) * 512 + 256 + h * 32 + e;
  for (int i = 0; i < 128; i += 2) {
    const float kv = (float)kp[(long)i * 512];
    const float ev = __expf(kv - Md);
#pragma unroll
    for (int d = 0; d < 32; ++d) acc[d] += __shfl(ev, d, 32) * kv;
  }
  float* cb = ctx + (long)bh * 1024;
#pragma unroll
  for (int d = 0; d < 32; ++d) {
    const float t = acc[d] + __shfl_xor(acc[d], 32);
    if (half == 0) atomicAdd(cb + d * 32 + e, t);
  }
}

// ---------------- linear attn: out[n,e] = sum_d softmax(q)[n,d]*scale * (ctx[d][e]*Sinv[d]) ----------------
__launch_bounds__(256)
__global__ void lout_kernel(const bf16* __restrict__ qkv, const float* __restrict__ Sinv,
                            const float* __restrict__ ctx, bf16* __restrict__ attn) {
  const int bh = blockIdx.x;
  const int b = bh / 7, h = bh % 7 + 1;
  const int w = threadIdx.x >> 6, lane = threadIdx.x & 63;
  const int e = lane & 31, half = lane >> 5;
  float creg[32];
#pragma unroll
  for (int d = 0; d < 32; ++d)
    creg[d] = ctx[(long)bh * 1024 + d * 32 + e] * Sinv[bh * 32 + d];
  const long tok0 = (long)blockIdx.y * 512 + w * 128 + half;
  const float scale = 0.17677669529663687f;
  const bf16* qp = qkv + ((long)b * 8192 + tok0) * 512 + h * 32 + e;
  bf16* op = attn + ((long)b * 8192 + tok0) * 256 + h * 32 + e;
  for (int i = 0; i < 128; i += 2) {
    const float qv = (float)qp[(long)i * 512];
    float mq = qv;
#pragma unroll
    for (int o = 1; o < 32; o <<= 1) mq = fmaxf(mq, __shfl_xor(mq, o));
    const float eq = __expf(qv - mq);
    float sq = eq;
#pragma unroll
    for (int o = 1; o < 32; o <<= 1) sq += __shfl_xor(sq, o);
    const float qs = eq * scale / sq;
    float ov = 0.f;
#pragma unroll
    for (int d = 0; d < 32; ++d) ov += __shfl(qs, d, 32) * creg[d];
    op[(long)i * 256] = (bf16)ov;
  }
}

extern "C" void kernel_launch(void* const* d_in, const int* in_sizes, int n_in,
                              void* d_out, int out_size, void* d_ws, size_t ws_size,
                              hipStream_t stream) {
  const float* x     = (const float*)d_in[0];
  const float* n1g   = (const float*)d_in[1];
  const float* n1b   = (const float*)d_in[2];
  const float* Wq    = (const float*)d_in[3];
  const float* Wkv   = (const float*)d_in[4];
  const float* Wproj = (const float*)d_in[5];
  const float* bproj = (const float*)d_in[6];
  const float* n2g   = (const float*)d_in[7];
  const float* n2b   = (const float*)d_in[8];
  const float* W1    = (const float*)d_in[9];
  const float* b1    = (const float*)d_in[10];
  const float* W2    = (const float*)d_in[11];
  const float* b2    = (const float*)d_in[12];
  float* out = (float*)d_out;
  char* ws = (char*)d_ws;

  // ws layout (all offsets 16B-aligned)
  bf16* wqkv   = (bf16*)(ws + 0);          // 512x256 bf16       = 262144 B
  bf16* wprojb = (bf16*)(ws + 262144);     // 256x256 bf16       = 131072 B
  bf16* w1b    = (bf16*)(ws + 393216);     // 1024x256 bf16      = 524288 B
  bf16* w2b    = (bf16*)(ws + 917504);     // 256x1024 bf16      = 524288 B
  float* Mx    = (float*)(ws + 1441792);   // 56*32 f32          = 7168 B
  float* Sinv  = (float*)(ws + 1448960);   // 56*32 f32          = 7168 B
  float* ctx   = (float*)(ws + 1456128);   // 56*1024 f32        = 229376 B
  bf16* hbuf   = (bf16*)(ws + 1685504);    // 65536x256 bf16     = 33554432 B  (h1 -> attn -> h2)
  bf16* qkv    = (bf16*)(ws + 35239936);   // 65536x512 bf16     = 67108864 B
  bf16* hidden = qkv;                      // 65536x1024 bf16 reuses qkv region = 134217728 B
  // total ws usage: 169457664 B

  cvt_weights<<<2816, 256, 0, stream>>>(Wq, Wkv, Wproj, W1, W2, wqkv, wprojb, w1b, w2b);
  ln_kernel<<<16384, 256, 0, stream>>>(x, n1g, n1b, hbuf);
  gemm_kernel<0><<<dim3(4, 512), 256, 0, stream>>>(hbuf, wqkv, qkv, nullptr, nullptr, 512, 256);
  lattn_kernel<<<dim3(128, 8), 256, 0, stream>>>(qkv, hbuf);
  kstats_kernel<<<56, 256, 0, stream>>>(qkv, Mx, Sinv);
  hipMemsetAsync(ctx, 0, 56 * 1024 * 4, stream);
  ctx_kernel<<<dim3(56, 16), 256, 0, stream>>>(qkv, Mx, ctx);
  lout_kernel<<<dim3(56, 16), 256, 0, stream>>>(qkv, Sinv, ctx, hbuf);
  gemm_kernel<1><<<dim3(2, 512), 256, 0, stream>>>(hbuf, wprojb, out, bproj, x, 256, 256);
  ln_kernel<<<16384, 256, 0, stream>>>(out, n2g, n2b, hbuf);
  gemm_kernel<2><<<dim3(8, 512), 256, 0, stream>>>(hbuf, w1b, hidden, b1, nullptr, 1024, 256);
  gemm_kernel<1><<<dim3(2, 512), 256, 0, stream>>>(hidden, w2b, out, b2, out, 256, 1024);
}

// Round 2
// 569.372 us; speedup vs baseline: 1.8031x; 1.8031x over previous
//
#include <hip/hip_runtime.h>
#include <hip/hip_bf16.h>

typedef __bf16 bf16;
typedef __bf16 bf16x8 __attribute__((ext_vector_type(8)));
typedef float f32x4 __attribute__((ext_vector_type(4)));

__device__ __forceinline__ void gld16(const void* g, void* l) {
  __builtin_amdgcn_global_load_lds((const __attribute__((address_space(1))) void*)g,
                                   (__attribute__((address_space(3))) void*)l, 16, 0, 0);
}

// ---------------- weight fp32 -> bf16 convert ----------------
__global__ void cvt_weights(const float* __restrict__ wq, const float* __restrict__ wkv,
                            const float* __restrict__ wp, const float* __restrict__ w1,
                            const float* __restrict__ w2,
                            bf16* __restrict__ wqkv, bf16* __restrict__ wpb,
                            bf16* __restrict__ w1b, bf16* __restrict__ w2b) {
  int i = blockIdx.x * 256 + threadIdx.x;
  if (i < 65536) wqkv[i] = (bf16)wq[i];
  else if (i < 131072) wqkv[i] = (bf16)wkv[i - 65536];
  else if (i < 196608) wpb[i - 131072] = (bf16)wp[i - 131072];
  else if (i < 458752) w1b[i - 196608] = (bf16)w1[i - 196608];
  else if (i < 720896) w2b[i - 458752] = (bf16)w2[i - 458752];
}

// ---------------- LayerNorm (wave per row, rows of 256) ----------------
__launch_bounds__(256)
__global__ void ln_kernel(const float* __restrict__ x, const float* __restrict__ g,
                          const float* __restrict__ b, bf16* __restrict__ out) {
  const int row = blockIdx.x * 4 + (threadIdx.x >> 6);
  const int lane = threadIdx.x & 63;
  const float4 v = ((const float4*)(x + (long)row * 256))[lane];
  float s = v.x + v.y + v.z + v.w;
#pragma unroll
  for (int o = 1; o < 64; o <<= 1) s += __shfl_xor(s, o);
  const float mu = s * (1.f / 256.f);
  const float dx = v.x - mu, dy = v.y - mu, dz = v.z - mu, dw = v.w - mu;
  float q = dx * dx + dy * dy + dz * dz + dw * dw;
#pragma unroll
  for (int o = 1; o < 64; o <<= 1) q += __shfl_xor(q, o);
  const float rstd = rsqrtf(q * (1.f / 256.f) + 1e-5f);
  const float4 gg = ((const float4*)g)[lane];
  const float4 bb = ((const float4*)b)[lane];
  union { bf16 h[4]; uint2 u; } pk;
  pk.h[0] = (bf16)(dx * rstd * gg.x + bb.x);
  pk.h[1] = (bf16)(dy * rstd * gg.y + bb.y);
  pk.h[2] = (bf16)(dz * rstd * gg.z + bb.z);
  pk.h[3] = (bf16)(dw * rstd * gg.w + bb.w);
  *(uint2*)(out + (long)row * 256 + lane * 4) = pk.u;
}

// ---------------- bf16 MFMA GEMM: C[M x Nn] = A[M x K] @ B[Nn x K]^T ----------------
// EPI 0: store bf16. EPI 1: f32 store of acc + bias[col] + res[idx]. EPI 2: bf16 store of gelu(acc+bias).
template <int EPI>
__launch_bounds__(256)
__global__ void gemm_kernel(const bf16* __restrict__ A, const bf16* __restrict__ B,
                            void* C, const float* __restrict__ bias,
                            const float* res, int Nn, int K) {
  __shared__ bf16 Alds[128 * 64];
  __shared__ bf16 Blds[128 * 64];
  const int tid = threadIdx.x;
  const int w = tid >> 6, lane = tid & 63;
  const int wr = w >> 1, wc = w & 1;
  const long m0 = (long)blockIdx.y * 128;
  const long n0 = (long)blockIdx.x * 128;
  const int srow = lane >> 3;
  const int scol = (lane & 7) * 8;
  f32x4 acc[4][4] = {};
  for (int kt = 0; kt < K; kt += 64) {
#pragma unroll
    for (int i = 0; i < 4; ++i) {
      const int c = w * 4 + i;
      const int row = c * 8 + srow;
      gld16(A + (m0 + row) * K + kt + scol, Alds + c * 512);
      gld16(B + (n0 + row) * K + kt + scol, Blds + c * 512);
    }
    asm volatile("s_waitcnt vmcnt(0)" ::: "memory");
    __syncthreads();
#pragma unroll
    for (int ks = 0; ks < 2; ++ks) {
      const int colo = ks * 32 + (lane >> 4) * 8;
      bf16x8 af[4], bfr[4];
#pragma unroll
      for (int fm = 0; fm < 4; ++fm)
        af[fm] = *(const bf16x8*)(Alds + (wr * 64 + fm * 16 + (lane & 15)) * 64 + colo);
#pragma unroll
      for (int fn = 0; fn < 4; ++fn)
        bfr[fn] = *(const bf16x8*)(Blds + (wc * 64 + fn * 16 + (lane & 15)) * 64 + colo);
#pragma unroll
      for (int fm = 0; fm < 4; ++fm)
#pragma unroll
        for (int fn = 0; fn < 4; ++fn)
          acc[fm][fn] = __builtin_amdgcn_mfma_f32_16x16x32_bf16(af[fm], bfr[fn], acc[fm][fn], 0, 0, 0);
    }
    __syncthreads();
  }
#pragma unroll
  for (int fm = 0; fm < 4; ++fm)
#pragma unroll
    for (int fn = 0; fn < 4; ++fn)
#pragma unroll
      for (int r = 0; r < 4; ++r) {
        const long row = m0 + wr * 64 + fm * 16 + (lane >> 4) * 4 + r;
        const long col = n0 + wc * 64 + fn * 16 + (lane & 15);
        const long idx = row * Nn + col;
        const float v = acc[fm][fn][r];
        if constexpr (EPI == 0) {
          ((bf16*)C)[idx] = (bf16)v;
        } else if constexpr (EPI == 1) {
          ((float*)C)[idx] = v + bias[col] + res[idx];
        } else {
          const float t = v + bias[col];
          ((bf16*)C)[idx] = (bf16)(0.5f * t * (1.f + erff(t * 0.70710678118654752f)));
        }
      }
}

// ---------------- local window attention (head 0), one block per (window, batch) ----------------
__launch_bounds__(256)
__global__ void lattn_kernel(const bf16* __restrict__ qkv, bf16* __restrict__ attn) {
  const int j = blockIdx.x, b = blockIdx.y;
  const int tid = threadIdx.x, w = tid >> 6, lane = tid & 63;
  __shared__ bf16 Qs[64 * 40];        // [row][d] stride 40
  __shared__ bf16 Ks[192 * 40];       // [c][d]   stride 40
  __shared__ bf16 Kt[32 * 200];       // [d][c]   stride 200
  __shared__ bf16 Ps[4][16 * 200];    // per-wave P [row16][c] stride 200
  const float scale = 0.17677669529663687f;  // 32^-0.5
  const long base = (long)b * 8192 + (long)j * 64;
  for (int i = tid; i < 64 * 32; i += 256) {
    const int r = i >> 5, d = i & 31;
    Qs[r * 40 + d] = (bf16)((float)qkv[(base + r) * 512 + d] * scale);
  }
  for (int i = tid; i < 192 * 32; i += 256) {
    const int c = i >> 5, d = i & 31;
    const long tc = (long)j * 64 - 64 + c;
    float kv = 0.f;
    if (tc >= 0 && tc < 8192) kv = (float)qkv[((long)b * 8192 + tc) * 512 + 256 + d];
    const bf16 kb = (bf16)kv;   // k == v (both from kv projection)
    Ks[c * 40 + d] = kb;
    Kt[d * 200 + c] = kb;
  }
  __syncthreads();
  const int l15 = lane & 15, l4 = lane >> 4;
  const bf16x8 aq = *(const bf16x8*)(Qs + (w * 16 + l15) * 40 + l4 * 8);
  const f32x4 zz = {0.f, 0.f, 0.f, 0.f};
  f32x4 S[12];
#pragma unroll
  for (int fn = 0; fn < 12; ++fn) {
    const bf16x8 bk = *(const bf16x8*)(Ks + (fn * 16 + l15) * 40 + l4 * 8);
    S[fn] = __builtin_amdgcn_mfma_f32_16x16x32_bf16(aq, bk, zz, 0, 0, 0);
  }
#pragma unroll
  for (int fn = 0; fn < 12; ++fn) {
    const long tc = (long)j * 64 - 64 + fn * 16 + l15;
    if (tc < 0 || tc >= 8192) { S[fn][0] = -1e9f; S[fn][1] = -1e9f; S[fn][2] = -1e9f; S[fn][3] = -1e9f; }
  }
  float sinv[4];
#pragma unroll
  for (int r = 0; r < 4; ++r) {
    float m = -1e30f;
#pragma unroll
    for (int fn = 0; fn < 12; ++fn) m = fmaxf(m, S[fn][r]);
#pragma unroll
    for (int o = 1; o < 16; o <<= 1) m = fmaxf(m, __shfl_xor(m, o));
    float s = 0.f;
#pragma unroll
    for (int fn = 0; fn < 12; ++fn) { const float e = __expf(S[fn][r] - m); S[fn][r] = e; s += e; }
#pragma unroll
    for (int o = 1; o < 16; o <<= 1) s += __shfl_xor(s, o);
    sinv[r] = 1.f / s;
  }
#pragma unroll
  for (int fn = 0; fn < 12; ++fn)
#pragma unroll
    for (int r = 0; r < 4; ++r)
      Ps[w][(l4 * 4 + r) * 200 + fn * 16 + l15] = (bf16)(S[fn][r] * sinv[r]);
  __syncthreads();
  f32x4 O[2] = {};
#pragma unroll
  for (int ks = 0; ks < 6; ++ks) {
    const bf16x8 ap = *(const bf16x8*)(Ps[w] + l15 * 200 + ks * 32 + l4 * 8);
#pragma unroll
    for (int fe = 0; fe < 2; ++fe) {
      const bf16x8 bv = *(const bf16x8*)(Kt + (fe * 16 + l15) * 200 + ks * 32 + l4 * 8);
      O[fe] = __builtin_amdgcn_mfma_f32_16x16x32_bf16(ap, bv, O[fe], 0, 0, 0);
    }
  }
#pragma unroll
  for (int fe = 0; fe < 2; ++fe)
#pragma unroll
    for (int r = 0; r < 4; ++r)
      attn[(base + w * 16 + l4 * 4 + r) * 256 + fe * 16 + l15] = (bf16)O[fe][r];
}

// ---------------- linear attn: fused ctx[d][e] += sum_n exp(k[n,d])*k[n,e]
//                  and column expsum S[d] += sum_n exp(k[n,d])  (no max needed:
//                  k = LN(x)@Wkv with sigma~0.32, |k| <~ 3, exp(k) safe in f32) ----------------
__launch_bounds__(256)
__global__ void ctx_kernel(const bf16* __restrict__ qkv, float* __restrict__ ctx,
                           float* __restrict__ S) {
  const int bh = blockIdx.x;
  const int b = bh / 7, h = bh % 7 + 1;
  const int w = threadIdx.x >> 6, lane = threadIdx.x & 63;
  const int e = lane & 31, half = lane >> 5;
  float acc[32];
#pragma unroll
  for (int d = 0; d < 32; ++d) acc[d] = 0.f;
  float ssum = 0.f;
  const long tok0 = (long)blockIdx.y * 256 + w * 64 + half;
  const bf16* kp = qkv + ((long)b * 8192 + tok0) * 512 + 256 + h * 32 + e;
  for (int i = 0; i < 64; i += 2) {
    const float kv = (float)kp[(long)i * 512];
    const float ev = __expf(kv);
    ssum += ev;
#pragma unroll
    for (int d = 0; d < 32; ++d) acc[d] += __shfl(ev, d, 32) * kv;
  }
  __shared__ float red[4][1024];
  __shared__ float sred[4][32];
#pragma unroll
  for (int d = 0; d < 32; ++d) {
    const float t = acc[d] + __shfl_xor(acc[d], 32);
    if (half == 0) red[w][d * 32 + e] = t;
  }
  ssum += __shfl_xor(ssum, 32);
  if (half == 0) sred[w][e] = ssum;
  __syncthreads();
  const int t0 = threadIdx.x;
#pragma unroll
  for (int r = 0; r < 4; ++r) {
    const int idx = r * 256 + t0;
    atomicAdd(ctx + (long)bh * 1024 + idx, red[0][idx] + red[1][idx] + red[2][idx] + red[3][idx]);
  }
  if (t0 < 32) atomicAdd(S + bh * 32 + t0, sred[0][t0] + sred[1][t0] + sred[2][t0] + sred[3][t0]);
}

// ---------------- linear attn: out[n,e] = sum_d softmax(q)[n,d]*scale * (ctx[d][e]/S[d]) ----------------
__launch_bounds__(256)
__global__ void lout_kernel(const bf16* __restrict__ qkv, const float* __restrict__ S,
                            const float* __restrict__ ctx, bf16* __restrict__ attn) {
  const int bh = blockIdx.x;
  const int b = bh / 7, h = bh % 7 + 1;
  const int w = threadIdx.x >> 6, lane = threadIdx.x & 63;
  const int e = lane & 31, half = lane >> 5;
  float creg[32];
#pragma unroll
  for (int d = 0; d < 32; ++d)
    creg[d] = ctx[(long)bh * 1024 + d * 32 + e] / S[bh * 32 + d];
  const long tok0 = (long)blockIdx.y * 512 + w * 128 + half;
  const float scale = 0.17677669529663687f;
  const bf16* qp = qkv + ((long)b * 8192 + tok0) * 512 + h * 32 + e;
  bf16* op = attn + ((long)b * 8192 + tok0) * 256 + h * 32 + e;
  for (int i = 0; i < 128; i += 2) {
    const float qv = (float)qp[(long)i * 512];
    float mq = qv;
#pragma unroll
    for (int o = 1; o < 32; o <<= 1) mq = fmaxf(mq, __shfl_xor(mq, o));
    const float eq = __expf(qv - mq);
    float sq = eq;
#pragma unroll
    for (int o = 1; o < 32; o <<= 1) sq += __shfl_xor(sq, o);
    const float qs = eq * scale / sq;
    float ov = 0.f;
#pragma unroll
    for (int d = 0; d < 32; ++d) ov += __shfl(qs, d, 32) * creg[d];
    op[(long)i * 256] = (bf16)ov;
  }
}

extern "C" void kernel_launch(void* const* d_in, const int* in_sizes, int n_in,
                              void* d_out, int out_size, void* d_ws, size_t ws_size,
                              hipStream_t stream) {
  const float* x     = (const float*)d_in[0];
  const float* n1g   = (const float*)d_in[1];
  const float* n1b   = (const float*)d_in[2];
  const float* Wq    = (const float*)d_in[3];
  const float* Wkv   = (const float*)d_in[4];
  const float* Wproj = (const float*)d_in[5];
  const float* bproj = (const float*)d_in[6];
  const float* n2g   = (const float*)d_in[7];
  const float* n2b   = (const float*)d_in[8];
  const float* W1    = (const float*)d_in[9];
  const float* b1    = (const float*)d_in[10];
  const float* W2    = (const float*)d_in[11];
  const float* b2    = (const float*)d_in[12];
  float* out = (float*)d_out;
  char* ws = (char*)d_ws;

  // ws layout (all offsets 16B-aligned)
  bf16* wqkv   = (bf16*)(ws + 0);          // 512x256 bf16       = 262144 B
  bf16* wprojb = (bf16*)(ws + 262144);     // 256x256 bf16       = 131072 B
  bf16* w1b    = (bf16*)(ws + 393216);     // 1024x256 bf16      = 524288 B
  bf16* w2b    = (bf16*)(ws + 917504);     // 256x1024 bf16      = 524288 B
  float* Sbuf  = (float*)(ws + 1441792);   // 56*32 f32          = 7168 B
  float* ctx   = (float*)(ws + 1448960);   // 56*1024 f32        = 229376 B  (contiguous w/ Sbuf for one memset)
  bf16* hbuf   = (bf16*)(ws + 1685504);    // 65536x256 bf16     = 33554432 B  (h1 -> attn -> h2)
  bf16* qkv    = (bf16*)(ws + 35239936);   // 65536x512 bf16     = 67108864 B
  bf16* hidden = qkv;                      // 65536x1024 bf16 reuses qkv region = 134217728 B
  // total ws usage: 169457664 B

  cvt_weights<<<2816, 256, 0, stream>>>(Wq, Wkv, Wproj, W1, W2, wqkv, wprojb, w1b, w2b);
  ln_kernel<<<16384, 256, 0, stream>>>(x, n1g, n1b, hbuf);
  gemm_kernel<0><<<dim3(4, 512), 256, 0, stream>>>(hbuf, wqkv, qkv, nullptr, nullptr, 512, 256);
  hipMemsetAsync(Sbuf, 0, 7168 + 229376, stream);
  lattn_kernel<<<dim3(128, 8), 256, 0, stream>>>(qkv, hbuf);
  ctx_kernel<<<dim3(56, 32), 256, 0, stream>>>(qkv, ctx, Sbuf);
  lout_kernel<<<dim3(56, 16), 256, 0, stream>>>(qkv, Sbuf, ctx, hbuf);
  gemm_kernel<1><<<dim3(2, 512), 256, 0, stream>>>(hbuf, wprojb, out, bproj, x, 256, 256);
  ln_kernel<<<16384, 256, 0, stream>>>(out, n2g, n2b, hbuf);
  gemm_kernel<2><<<dim3(8, 512), 256, 0, stream>>>(hbuf, w1b, hidden, b1, nullptr, 1024, 256);
  gemm_kernel<1><<<dim3(2, 512), 256, 0, stream>>>(hidden, w2b, out, b2, out, 256, 1024);
}

// Round 3
// 412.236 us; speedup vs baseline: 2.4904x; 1.3812x over previous
//
#include <hip/hip_runtime.h>
#include <hip/hip_bf16.h>

typedef __bf16 bf16;
typedef __bf16 bf16x8 __attribute__((ext_vector_type(8)));
typedef float f32x4 __attribute__((ext_vector_type(4)));

__device__ __forceinline__ void gld16(const void* g, void* l) {
  __builtin_amdgcn_global_load_lds((const __attribute__((address_space(1))) void*)g,
                                   (__attribute__((address_space(3))) void*)l, 16, 0, 0);
}

// ---------------- weight fp32 -> bf16 convert ----------------
__global__ void cvt_weights(const float* __restrict__ wq, const float* __restrict__ wkv,
                            const float* __restrict__ wp, const float* __restrict__ w1,
                            const float* __restrict__ w2,
                            bf16* __restrict__ wqkv, bf16* __restrict__ wpb,
                            bf16* __restrict__ w1b, bf16* __restrict__ w2b) {
  int i = blockIdx.x * 256 + threadIdx.x;
  if (i < 65536) wqkv[i] = (bf16)wq[i];
  else if (i < 131072) wqkv[i] = (bf16)wkv[i - 65536];
  else if (i < 196608) wpb[i - 131072] = (bf16)wp[i - 131072];
  else if (i < 458752) w1b[i - 196608] = (bf16)w1[i - 196608];
  else if (i < 720896) w2b[i - 458752] = (bf16)w2[i - 458752];
}

// ---------------- LayerNorm (wave per row, rows of 256) ----------------
__launch_bounds__(256)
__global__ void ln_kernel(const float* __restrict__ x, const float* __restrict__ g,
                          const float* __restrict__ b, bf16* __restrict__ out) {
  const int row = blockIdx.x * 4 + (threadIdx.x >> 6);
  const int lane = threadIdx.x & 63;
  const float4 v = ((const float4*)(x + (long)row * 256))[lane];
  float s = v.x + v.y + v.z + v.w;
#pragma unroll
  for (int o = 1; o < 64; o <<= 1) s += __shfl_xor(s, o);
  const float mu = s * (1.f / 256.f);
  const float dx = v.x - mu, dy = v.y - mu, dz = v.z - mu, dw = v.w - mu;
  float q = dx * dx + dy * dy + dz * dz + dw * dw;
#pragma unroll
  for (int o = 1; o < 64; o <<= 1) q += __shfl_xor(q, o);
  const float rstd = rsqrtf(q * (1.f / 256.f) + 1e-5f);
  const float4 gg = ((const float4*)g)[lane];
  const float4 bb = ((const float4*)b)[lane];
  union { bf16 h[4]; uint2 u; } pk;
  pk.h[0] = (bf16)(dx * rstd * gg.x + bb.x);
  pk.h[1] = (bf16)(dy * rstd * gg.y + bb.y);
  pk.h[2] = (bf16)(dz * rstd * gg.z + bb.z);
  pk.h[3] = (bf16)(dw * rstd * gg.w + bb.w);
  *(uint2*)(out + (long)row * 256 + lane * 4) = pk.u;
}

// ---------------- bf16 MFMA GEMM: C[M x Nn] = A[M x K] @ B[Nn x K]^T ----------------
template <int EPI>
__launch_bounds__(256)
__global__ void gemm_kernel(const bf16* __restrict__ A, const bf16* __restrict__ B,
                            void* C, const float* __restrict__ bias,
                            const float* res, int Nn, int K) {
  __shared__ bf16 Alds[128 * 64];
  __shared__ bf16 Blds[128 * 64];
  const int tid = threadIdx.x;
  const int w = tid >> 6, lane = tid & 63;
  const int wr = w >> 1, wc = w & 1;
  const long m0 = (long)blockIdx.y * 128;
  const long n0 = (long)blockIdx.x * 128;
  const int srow = lane >> 3;
  const int scol = (lane & 7) * 8;
  f32x4 acc[4][4] = {};
  for (int kt = 0; kt < K; kt += 64) {
#pragma unroll
    for (int i = 0; i < 4; ++i) {
      const int c = w * 4 + i;
      const int row = c * 8 + srow;
      gld16(A + (m0 + row) * K + kt + scol, Alds + c * 512);
      gld16(B + (n0 + row) * K + kt + scol, Blds + c * 512);
    }
    asm volatile("s_waitcnt vmcnt(0)" ::: "memory");
    __syncthreads();
#pragma unroll
    for (int ks = 0; ks < 2; ++ks) {
      const int colo = ks * 32 + (lane >> 4) * 8;
      bf16x8 af[4], bfr[4];
#pragma unroll
      for (int fm = 0; fm < 4; ++fm)
        af[fm] = *(const bf16x8*)(Alds + (wr * 64 + fm * 16 + (lane & 15)) * 64 + colo);
#pragma unroll
      for (int fn = 0; fn < 4; ++fn)
        bfr[fn] = *(const bf16x8*)(Blds + (wc * 64 + fn * 16 + (lane & 15)) * 64 + colo);
#pragma unroll
      for (int fm = 0; fm < 4; ++fm)
#pragma unroll
        for (int fn = 0; fn < 4; ++fn)
          acc[fm][fn] = __builtin_amdgcn_mfma_f32_16x16x32_bf16(af[fm], bfr[fn], acc[fm][fn], 0, 0, 0);
    }
    __syncthreads();
  }
#pragma unroll
  for (int fm = 0; fm < 4; ++fm)
#pragma unroll
    for (int fn = 0; fn < 4; ++fn)
#pragma unroll
      for (int r = 0; r < 4; ++r) {
        const long row = m0 + wr * 64 + fm * 16 + (lane >> 4) * 4 + r;
        const long col = n0 + wc * 64 + fn * 16 + (lane & 15);
        const long idx = row * Nn + col;
        const float v = acc[fm][fn][r];
        if constexpr (EPI == 0) {
          ((bf16*)C)[idx] = (bf16)v;
        } else if constexpr (EPI == 1) {
          ((float*)C)[idx] = v + bias[col] + res[idx];
        } else {
          const float t = v + bias[col];
          ((bf16*)C)[idx] = (bf16)(0.5f * t * (1.f + erff(t * 0.70710678118654752f)));
        }
      }
}

// ---------------- local window attention (head 0), one block per (window, batch) ----------------
__launch_bounds__(256)
__global__ void lattn_kernel(const bf16* __restrict__ qkv, bf16* __restrict__ attn) {
  const int j = blockIdx.x, b = blockIdx.y;
  const int tid = threadIdx.x, w = tid >> 6, lane = tid & 63;
  __shared__ bf16 Qs[64 * 40];
  __shared__ bf16 Ks[192 * 40];
  __shared__ bf16 Kt[32 * 200];
  __shared__ bf16 Ps[4][16 * 200];
  const float scale = 0.17677669529663687f;
  const long base = (long)b * 8192 + (long)j * 64;
  for (int i = tid; i < 64 * 32; i += 256) {
    const int r = i >> 5, d = i & 31;
    Qs[r * 40 + d] = (bf16)((float)qkv[(base + r) * 512 + d] * scale);
  }
  for (int i = tid; i < 192 * 32; i += 256) {
    const int c = i >> 5, d = i & 31;
    const long tc = (long)j * 64 - 64 + c;
    float kv = 0.f;
    if (tc >= 0 && tc < 8192) kv = (float)qkv[((long)b * 8192 + tc) * 512 + 256 + d];
    const bf16 kb = (bf16)kv;
    Ks[c * 40 + d] = kb;
    Kt[d * 200 + c] = kb;
  }
  __syncthreads();
  const int l15 = lane & 15, l4 = lane >> 4;
  const bf16x8 aq = *(const bf16x8*)(Qs + (w * 16 + l15) * 40 + l4 * 8);
  const f32x4 zz = {0.f, 0.f, 0.f, 0.f};
  f32x4 S[12];
#pragma unroll
  for (int fn = 0; fn < 12; ++fn) {
    const bf16x8 bk = *(const bf16x8*)(Ks + (fn * 16 + l15) * 40 + l4 * 8);
    S[fn] = __builtin_amdgcn_mfma_f32_16x16x32_bf16(aq, bk, zz, 0, 0, 0);
  }
#pragma unroll
  for (int fn = 0; fn < 12; ++fn) {
    const long tc = (long)j * 64 - 64 + fn * 16 + l15;
    if (tc < 0 || tc >= 8192) { S[fn][0] = -1e9f; S[fn][1] = -1e9f; S[fn][2] = -1e9f; S[fn][3] = -1e9f; }
  }
  float sinv[4];
#pragma unroll
  for (int r = 0; r < 4; ++r) {
    float m = -1e30f;
#pragma unroll
    for (int fn = 0; fn < 12; ++fn) m = fmaxf(m, S[fn][r]);
#pragma unroll
    for (int o = 1; o < 16; o <<= 1) m = fmaxf(m, __shfl_xor(m, o));
    float s = 0.f;
#pragma unroll
    for (int fn = 0; fn < 12; ++fn) { const float e = __expf(S[fn][r] - m); S[fn][r] = e; s += e; }
#pragma unroll
    for (int o = 1; o < 16; o <<= 1) s += __shfl_xor(s, o);
    sinv[r] = 1.f / s;
  }
#pragma unroll
  for (int fn = 0; fn < 12; ++fn)
#pragma unroll
    for (int r = 0; r < 4; ++r)
      Ps[w][(l4 * 4 + r) * 200 + fn * 16 + l15] = (bf16)(S[fn][r] * sinv[r]);
  __syncthreads();
  f32x4 O[2] = {};
#pragma unroll
  for (int ks = 0; ks < 6; ++ks) {
    const bf16x8 ap = *(const bf16x8*)(Ps[w] + l15 * 200 + ks * 32 + l4 * 8);
#pragma unroll
    for (int fe = 0; fe < 2; ++fe) {
      const bf16x8 bv = *(const bf16x8*)(Kt + (fe * 16 + l15) * 200 + ks * 32 + l4 * 8);
      O[fe] = __builtin_amdgcn_mfma_f32_16x16x32_bf16(ap, bv, O[fe], 0, 0, 0);
    }
  }
#pragma unroll
  for (int fe = 0; fe < 2; ++fe)
#pragma unroll
    for (int r = 0; r < 4; ++r)
      attn[(base + w * 16 + l4 * 4 + r) * 256 + fe * 16 + l15] = (bf16)O[fe][r];
}

// ---------------- linear attn ctx via MFMA: ctx[d][e] = sum_n exp(k[n,d]) k[n,e];
//                  S[d] = sum_n exp(k[n,d]) via ones-row in B operand ----------------
__launch_bounds__(256)
__global__ void ctx_kernel(const bf16* __restrict__ qkv, float* __restrict__ ctx,
                           float* __restrict__ S) {
  const int bh = blockIdx.x;
  const int b = bh / 7, h = bh % 7 + 1;
  const int tid = threadIdx.x;
  const int w = tid >> 6, lane = tid & 63;
  const int l15 = lane & 15, l4 = lane >> 4;
  __shared__ bf16 evT[32 * 264];   // [d][n] token-transposed exp(k)
  __shared__ bf16 kT[48 * 264];    // [e][n]; rows 32..47: row32=ones (S), rest zero
  __shared__ float red[4][32 * 48];
  const long n0 = (long)blockIdx.y * 256;
  const bf16* kp = qkv + ((long)b * 8192 + n0 + tid) * 512 + 256 + h * 32;
  bf16x8 kv[4];
#pragma unroll
  for (int c = 0; c < 4; ++c) kv[c] = *(const bf16x8*)(kp + c * 8);
#pragma unroll
  for (int i = 0; i < 16; ++i)
    kT[(32 + i) * 264 + tid] = (i == 0) ? (bf16)1.0f : (bf16)0.0f;
#pragma unroll
  for (int c = 0; c < 4; ++c)
#pragma unroll
    for (int j = 0; j < 8; ++j) {
      const int d = c * 8 + j;
      evT[d * 264 + tid] = (bf16)__expf((float)kv[c][j]);
      kT[d * 264 + tid] = kv[c][j];
    }
  __syncthreads();
  f32x4 acc[2][3] = {};
#pragma unroll
  for (int ks = 0; ks < 2; ++ks) {
    const int ncol = w * 64 + ks * 32 + l4 * 8;
    bf16x8 af[2], bb[3];
#pragma unroll
    for (int fm = 0; fm < 2; ++fm) af[fm] = *(const bf16x8*)(evT + (fm * 16 + l15) * 264 + ncol);
#pragma unroll
    for (int fe = 0; fe < 3; ++fe) bb[fe] = *(const bf16x8*)(kT + (fe * 16 + l15) * 264 + ncol);
#pragma unroll
    for (int fm = 0; fm < 2; ++fm)
#pragma unroll
      for (int fe = 0; fe < 3; ++fe)
        acc[fm][fe] = __builtin_amdgcn_mfma_f32_16x16x32_bf16(af[fm], bb[fe], acc[fm][fe], 0, 0, 0);
  }
#pragma unroll
  for (int fm = 0; fm < 2; ++fm)
#pragma unroll
    for (int fe = 0; fe < 3; ++fe)
#pragma unroll
      for (int r = 0; r < 4; ++r)
        red[w][(fm * 16 + l4 * 4 + r) * 48 + fe * 16 + l15] = acc[fm][fe][r];
  __syncthreads();
  for (int i = tid; i < 32 * 48; i += 256) {
    const float v = red[0][i] + red[1][i] + red[2][i] + red[3][i];
    const int d = i / 48, e = i - d * 48;
    if (e < 32) atomicAdd(ctx + (long)bh * 1024 + d * 32 + e, v);
    else if (e == 32) atomicAdd(S + bh * 32 + d, v);
  }
}

// ---------------- linear attn out via register softmax + MFMA:
//                  out[n,e] = sum_d softmax(q)[n,d]*scale * (ctx[d][e]/S[d]) ----------------
__launch_bounds__(256)
__global__ void lout_kernel(const bf16* __restrict__ qkv, const float* __restrict__ S,
                            const float* __restrict__ ctx, bf16* __restrict__ attn) {
  const int bh = blockIdx.x;
  const int b = bh / 7, h = bh % 7 + 1;
  const int tid = threadIdx.x;
  const int w = tid >> 6, lane = tid & 63;
  const int l15 = lane & 15, l4 = lane >> 4;
  __shared__ bf16 qs[256 * 40];    // [n][d] softmaxed q, bf16
  __shared__ bf16 C2t[32 * 40];    // [e][d] = ctx[d][e]/S[d]
  const long n0 = (long)blockIdx.y * 256;
  for (int i = tid; i < 1024; i += 256) {
    const int e = i >> 5, d = i & 31;
    C2t[e * 40 + d] = (bf16)(ctx[(long)bh * 1024 + d * 32 + e] / S[bh * 32 + d]);
  }
  const bf16* qp = qkv + ((long)b * 8192 + n0 + tid) * 512 + h * 32;
  bf16x8 qv[4];
#pragma unroll
  for (int c = 0; c < 4; ++c) qv[c] = *(const bf16x8*)(qp + c * 8);
  float qf[32];
#pragma unroll
  for (int c = 0; c < 4; ++c)
#pragma unroll
    for (int j = 0; j < 8; ++j) qf[c * 8 + j] = (float)qv[c][j];
  float m = qf[0];
#pragma unroll
  for (int d = 1; d < 32; ++d) m = fmaxf(m, qf[d]);
  float s = 0.f;
#pragma unroll
  for (int d = 0; d < 32; ++d) { qf[d] = __expf(qf[d] - m); s += qf[d]; }
  const float f = 0.17677669529663687f / s;
#pragma unroll
  for (int c = 0; c < 4; ++c) {
    bf16x8 o;
#pragma unroll
    for (int j = 0; j < 8; ++j) o[j] = (bf16)(qf[c * 8 + j] * f);
    *(bf16x8*)(qs + tid * 40 + c * 8) = o;
  }
  __syncthreads();
  f32x4 acc[4][2] = {};
  bf16x8 bfr[2];
#pragma unroll
  for (int fe = 0; fe < 2; ++fe) bfr[fe] = *(const bf16x8*)(C2t + (fe * 16 + l15) * 40 + l4 * 8);
#pragma unroll
  for (int fm = 0; fm < 4; ++fm) {
    const bf16x8 af = *(const bf16x8*)(qs + (w * 64 + fm * 16 + l15) * 40 + l4 * 8);
#pragma unroll
    for (int fe = 0; fe < 2; ++fe)
      acc[fm][fe] = __builtin_amdgcn_mfma_f32_16x16x32_bf16(af, bfr[fe], acc[fm][fe], 0, 0, 0);
  }
#pragma unroll
  for (int fm = 0; fm < 4; ++fm)
#pragma unroll
    for (int fe = 0; fe < 2; ++fe)
#pragma unroll
      for (int r = 0; r < 4; ++r)
        attn[((long)b * 8192 + n0 + w * 64 + fm * 16 + l4 * 4 + r) * 256 + h * 32 + fe * 16 + l15]
            = (bf16)acc[fm][fe][r];
}

extern "C" void kernel_launch(void* const* d_in, const int* in_sizes, int n_in,
                              void* d_out, int out_size, void* d_ws, size_t ws_size,
                              hipStream_t stream) {
  const float* x     = (const float*)d_in[0];
  const float* n1g   = (const float*)d_in[1];
  const float* n1b   = (const float*)d_in[2];
  const float* Wq    = (const float*)d_in[3];
  const float* Wkv   = (const float*)d_in[4];
  const float* Wproj = (const float*)d_in[5];
  const float* bproj = (const float*)d_in[6];
  const float* n2g   = (const float*)d_in[7];
  const float* n2b   = (const float*)d_in[8];
  const float* W1    = (const float*)d_in[9];
  const float* b1    = (const float*)d_in[10];
  const float* W2    = (const float*)d_in[11];
  const float* b2    = (const float*)d_in[12];
  float* out = (float*)d_out;
  char* ws = (char*)d_ws;

  bf16* wqkv   = (bf16*)(ws + 0);
  bf16* wprojb = (bf16*)(ws + 262144);
  bf16* w1b    = (bf16*)(ws + 393216);
  bf16* w2b    = (bf16*)(ws + 917504);
  float* Sbuf  = (float*)(ws + 1441792);   // 56*32 f32, contiguous with ctx for one memset
  float* ctx   = (float*)(ws + 1448960);   // 56*1024 f32
  bf16* hbuf   = (bf16*)(ws + 1685504);    // 65536x256 bf16 (h1 -> attn -> h2)
  bf16* qkv    = (bf16*)(ws + 35239936);   // 65536x512 bf16
  bf16* hidden = qkv;                      // 65536x1024 bf16 reuses qkv region

  cvt_weights<<<2816, 256, 0, stream>>>(Wq, Wkv, Wproj, W1, W2, wqkv, wprojb, w1b, w2b);
  ln_kernel<<<16384, 256, 0, stream>>>(x, n1g, n1b, hbuf);
  gemm_kernel<0><<<dim3(4, 512), 256, 0, stream>>>(hbuf, wqkv, qkv, nullptr, nullptr, 512, 256);
  hipMemsetAsync(Sbuf, 0, 7168 + 229376, stream);
  lattn_kernel<<<dim3(128, 8), 256, 0, stream>>>(qkv, hbuf);
  ctx_kernel<<<dim3(56, 32), 256, 0, stream>>>(qkv, ctx, Sbuf);
  lout_kernel<<<dim3(56, 32), 256, 0, stream>>>(qkv, Sbuf, ctx, hbuf);
  gemm_kernel<1><<<dim3(2, 512), 256, 0, stream>>>(hbuf, wprojb, out, bproj, x, 256, 256);
  ln_kernel<<<16384, 256, 0, stream>>>(out, n2g, n2b, hbuf);
  gemm_kernel<2><<<dim3(8, 512), 256, 0, stream>>>(hbuf, w1b, hidden, b1, nullptr, 1024, 256);
  gemm_kernel<1><<<dim3(2, 512), 256, 0, stream>>>(hidden, w2b, out, b2, out, 256, 1024);
}

// Round 4
// 403.215 us; speedup vs baseline: 2.5461x; 1.0224x over previous
//
#include <hip/hip_runtime.h>
#include <hip/hip_bf16.h>

typedef __bf16 bf16;
typedef __bf16 bf16x8 __attribute__((ext_vector_type(8)));
typedef float f32x4 __attribute__((ext_vector_type(4)));

__device__ __forceinline__ void gld16(const void* g, void* l) {
  __builtin_amdgcn_global_load_lds((const __attribute__((address_space(1))) void*)g,
                                   (__attribute__((address_space(3))) void*)l, 16, 0, 0);
}

// ---------------- weight fp32 -> bf16 convert ----------------
__global__ void cvt_weights(const float* __restrict__ wq, const float* __restrict__ wkv,
                            const float* __restrict__ wp, const float* __restrict__ w1,
                            const float* __restrict__ w2,
                            bf16* __restrict__ wqkv, bf16* __restrict__ wpb,
                            bf16* __restrict__ w1b, bf16* __restrict__ w2b) {
  int i = blockIdx.x * 256 + threadIdx.x;
  if (i < 65536) wqkv[i] = (bf16)wq[i];
  else if (i < 131072) wqkv[i] = (bf16)wkv[i - 65536];
  else if (i < 196608) wpb[i - 131072] = (bf16)wp[i - 131072];
  else if (i < 458752) w1b[i - 196608] = (bf16)w1[i - 196608];
  else if (i < 720896) w2b[i - 458752] = (bf16)w2[i - 458752];
}

// ---------------- LayerNorm (wave per row, rows of 256) ----------------
__launch_bounds__(256)
__global__ void ln_kernel(const float* __restrict__ x, const float* __restrict__ g,
                          const float* __restrict__ b, bf16* __restrict__ out) {
  const int row = blockIdx.x * 4 + (threadIdx.x >> 6);
  const int lane = threadIdx.x & 63;
  const float4 v = ((const float4*)(x + (long)row * 256))[lane];
  float s = v.x + v.y + v.z + v.w;
#pragma unroll
  for (int o = 1; o < 64; o <<= 1) s += __shfl_xor(s, o);
  const float mu = s * (1.f / 256.f);
  const float dx = v.x - mu, dy = v.y - mu, dz = v.z - mu, dw = v.w - mu;
  float q = dx * dx + dy * dy + dz * dz + dw * dw;
#pragma unroll
  for (int o = 1; o < 64; o <<= 1) q += __shfl_xor(q, o);
  const float rstd = rsqrtf(q * (1.f / 256.f) + 1e-5f);
  const float4 gg = ((const float4*)g)[lane];
  const float4 bb = ((const float4*)b)[lane];
  union { bf16 h[4]; uint2 u; } pk;
  pk.h[0] = (bf16)(dx * rstd * gg.x + bb.x);
  pk.h[1] = (bf16)(dy * rstd * gg.y + bb.y);
  pk.h[2] = (bf16)(dz * rstd * gg.z + bb.z);
  pk.h[3] = (bf16)(dw * rstd * gg.w + bb.w);
  *(uint2*)(out + (long)row * 256 + lane * 4) = pk.u;
}

// ---------------- B-direct GEMM: C[M x ldC](cols n_base..n_base+NTILE) = A[M x KK] @ B[NTILE x KK]^T
// A staged in LDS (ping-pong K-chunks, XOR-swizzled, counted-vmcnt overlap);
// B fragments loaded directly global->VGPR (weights are L2-resident).
// 8 waves, each owns CW=NTILE/8 columns and all MT rows (WR=1).
// EPI 0: bf16 store. EPI 1: f32 store acc+bias+res. EPI 2: bf16 store gelu(acc+bias).
template <int EPI, int MT, int NTILE, int KK, int NCHUNK>
__launch_bounds__(512, 4)
__global__ void gemm_bd(const bf16* __restrict__ A, const bf16* __restrict__ B,
                        void* C, const float* __restrict__ bias,
                        const float* res, int ldC) {
  constexpr int CW = NTILE / 8;       // cols per wave
  constexpr int FM = MT / 16;         // row fragments
  constexpr int FN = CW / 16;         // col fragments per wave
  constexpr int CK = KK / NCHUNK;     // K per chunk
  constexpr int RSB = 2 * CK;         // LDS row stride bytes
  constexpr int LROW = (RSB == 256) ? 8 : ((RSB == 512) ? 9 : 10);
  constexpr int CHB = MT * CK * 2;    // chunk bytes
  constexpr int ITER = CHB / (512 * 16);
  __shared__ bf16 lds[2 * MT * CK];
  const int tid = threadIdx.x;
  const int w = tid >> 6, lane = tid & 63;
  const int l15 = lane & 15, l4 = lane >> 4;
  const int swz = (l15 & 7) << 4;
  const long m0 = (long)blockIdx.x * MT;
  const int n_base = blockIdx.y * NTILE;
  const bf16* Bl = B + ((long)(n_base + w * CW + l15)) * KK + l4 * 8;

  f32x4 acc[FM][FN] = {};

  // ---- stage chunk helper (inlined via macro-ish lambda) ----
  auto stage = [&](int c, int buf) {
#pragma unroll
    for (int it = 0; it < ITER; ++it) {
      const int p = it * 8192 + tid * 16;             // byte offset within chunk
      const int row = p >> LROW;
      const int colb = (p & (RSB - 1)) ^ ((row & 7) << 4);
      gld16((const char*)A + ((m0 + row) * KK + (long)c * CK) * 2 + colb,
            (char*)lds + buf * CHB + it * 8192 + w * 1024);
    }
  };

  stage(0, 0);
  asm volatile("s_waitcnt vmcnt(0)" ::: "memory");
  __syncthreads();

  for (int c = 0; c < NCHUNK; ++c) {
    if (c + 1 < NCHUNK) stage(c + 1, (c + 1) & 1);
    const char* base = (const char*)lds + (c & 1) * CHB;
#pragma unroll
    for (int kl = 0; kl < CK / 32; ++kl) {
      bf16x8 bfrag[FN];
#pragma unroll
      for (int fn = 0; fn < FN; ++fn)
        bfrag[fn] = *(const bf16x8*)(Bl + (long)fn * 16 * KK + c * CK + kl * 32);
      bf16x8 afrag[FM];
#pragma unroll
      for (int fm = 0; fm < FM; ++fm)
        afrag[fm] = *(const bf16x8*)(base + (fm * 16 + l15) * RSB + ((kl * 64 + l4 * 16) ^ swz));
#pragma unroll
      for (int fm = 0; fm < FM; ++fm)
#pragma unroll
        for (int fn = 0; fn < FN; ++fn)
          acc[fm][fn] = __builtin_amdgcn_mfma_f32_16x16x32_bf16(afrag[fm], bfrag[fn], acc[fm][fn], 0, 0, 0);
    }
    if (c + 1 < NCHUNK) {
      asm volatile("s_waitcnt vmcnt(0)" ::: "memory");
      __syncthreads();
    }
  }

#pragma unroll
  for (int fm = 0; fm < FM; ++fm)
#pragma unroll
    for (int fn = 0; fn < FN; ++fn)
#pragma unroll
      for (int r = 0; r < 4; ++r) {
        const long row = m0 + fm * 16 + l4 * 4 + r;
        const int col = n_base + w * CW + fn * 16 + l15;
        const long idx = row * ldC + col;
        const float v = acc[fm][fn][r];
        if constexpr (EPI == 0) {
          ((bf16*)C)[idx] = (bf16)v;
        } else if constexpr (EPI == 1) {
          ((float*)C)[idx] = v + bias[col] + res[idx];
        } else {
          const float t = v + bias[col];
          ((bf16*)C)[idx] = (bf16)(0.5f * t * (1.f + erff(t * 0.70710678118654752f)));
        }
      }
}

// ---------------- local window attention (head 0), one block per (window, batch) ----------------
__launch_bounds__(256)
__global__ void lattn_kernel(const bf16* __restrict__ qkv, bf16* __restrict__ attn) {
  const int j = blockIdx.x, b = blockIdx.y;
  const int tid = threadIdx.x, w = tid >> 6, lane = tid & 63;
  __shared__ bf16 Qs[64 * 40];
  __shared__ bf16 Ks[192 * 40];
  __shared__ bf16 Kt[32 * 200];
  __shared__ bf16 Ps[4][16 * 200];
  const float scale = 0.17677669529663687f;
  const long base = (long)b * 8192 + (long)j * 64;
  for (int i = tid; i < 64 * 32; i += 256) {
    const int r = i >> 5, d = i & 31;
    Qs[r * 40 + d] = (bf16)((float)qkv[(base + r) * 512 + d] * scale);
  }
  for (int i = tid; i < 192 * 32; i += 256) {
    const int c = i >> 5, d = i & 31;
    const long tc = (long)j * 64 - 64 + c;
    float kv = 0.f;
    if (tc >= 0 && tc < 8192) kv = (float)qkv[((long)b * 8192 + tc) * 512 + 256 + d];
    const bf16 kb = (bf16)kv;
    Ks[c * 40 + d] = kb;
    Kt[d * 200 + c] = kb;
  }
  __syncthreads();
  const int l15 = lane & 15, l4 = lane >> 4;
  const bf16x8 aq = *(const bf16x8*)(Qs + (w * 16 + l15) * 40 + l4 * 8);
  const f32x4 zz = {0.f, 0.f, 0.f, 0.f};
  f32x4 S[12];
#pragma unroll
  for (int fn = 0; fn < 12; ++fn) {
    const bf16x8 bk = *(const bf16x8*)(Ks + (fn * 16 + l15) * 40 + l4 * 8);
    S[fn] = __builtin_amdgcn_mfma_f32_16x16x32_bf16(aq, bk, zz, 0, 0, 0);
  }
#pragma unroll
  for (int fn = 0; fn < 12; ++fn) {
    const long tc = (long)j * 64 - 64 + fn * 16 + l15;
    if (tc < 0 || tc >= 8192) { S[fn][0] = -1e9f; S[fn][1] = -1e9f; S[fn][2] = -1e9f; S[fn][3] = -1e9f; }
  }
  float sinv[4];
#pragma unroll
  for (int r = 0; r < 4; ++r) {
    float m = -1e30f;
#pragma unroll
    for (int fn = 0; fn < 12; ++fn) m = fmaxf(m, S[fn][r]);
#pragma unroll
    for (int o = 1; o < 16; o <<= 1) m = fmaxf(m, __shfl_xor(m, o));
    float s = 0.f;
#pragma unroll
    for (int fn = 0; fn < 12; ++fn) { const float e = __expf(S[fn][r] - m); S[fn][r] = e; s += e; }
#pragma unroll
    for (int o = 1; o < 16; o <<= 1) s += __shfl_xor(s, o);
    sinv[r] = 1.f / s;
  }
#pragma unroll
  for (int fn = 0; fn < 12; ++fn)
#pragma unroll
    for (int r = 0; r < 4; ++r)
      Ps[w][(l4 * 4 + r) * 200 + fn * 16 + l15] = (bf16)(S[fn][r] * sinv[r]);
  __syncthreads();
  f32x4 O[2] = {};
#pragma unroll
  for (int ks = 0; ks < 6; ++ks) {
    const bf16x8 ap = *(const bf16x8*)(Ps[w] + l15 * 200 + ks * 32 + l4 * 8);
#pragma unroll
    for (int fe = 0; fe < 2; ++fe) {
      const bf16x8 bv = *(const bf16x8*)(Kt + (fe * 16 + l15) * 200 + ks * 32 + l4 * 8);
      O[fe] = __builtin_amdgcn_mfma_f32_16x16x32_bf16(ap, bv, O[fe], 0, 0, 0);
    }
  }
#pragma unroll
  for (int fe = 0; fe < 2; ++fe)
#pragma unroll
    for (int r = 0; r < 4; ++r)
      attn[(base + w * 16 + l4 * 4 + r) * 256 + fe * 16 + l15] = (bf16)O[fe][r];
}

// ---------------- linear attn ctx via MFMA: ctx[d][e] = sum_n exp(k[n,d]) k[n,e];
//                  S[d] = sum_n exp(k[n,d]) via ones-row in B operand ----------------
__launch_bounds__(256)
__global__ void ctx_kernel(const bf16* __restrict__ qkv, float* __restrict__ ctx,
                           float* __restrict__ S) {
  const int bh = blockIdx.x;
  const int b = bh / 7, h = bh % 7 + 1;
  const int tid = threadIdx.x;
  const int w = tid >> 6, lane = tid & 63;
  const int l15 = lane & 15, l4 = lane >> 4;
  __shared__ bf16 evT[32 * 264];
  __shared__ bf16 kT[48 * 264];
  __shared__ float red[4][32 * 48];
  const long n0 = (long)blockIdx.y * 256;
  const bf16* kp = qkv + ((long)b * 8192 + n0 + tid) * 512 + 256 + h * 32;
  bf16x8 kv[4];
#pragma unroll
  for (int c = 0; c < 4; ++c) kv[c] = *(const bf16x8*)(kp + c * 8);
#pragma unroll
  for (int i = 0; i < 16; ++i)
    kT[(32 + i) * 264 + tid] = (i == 0) ? (bf16)1.0f : (bf16)0.0f;
#pragma unroll
  for (int c = 0; c < 4; ++c)
#pragma unroll
    for (int j = 0; j < 8; ++j) {
      const int d = c * 8 + j;
      evT[d * 264 + tid] = (bf16)__expf((float)kv[c][j]);
      kT[d * 264 + tid] = kv[c][j];
    }
  __syncthreads();
  f32x4 acc[2][3] = {};
#pragma unroll
  for (int ks = 0; ks < 2; ++ks) {
    const int ncol = w * 64 + ks * 32 + l4 * 8;
    bf16x8 af[2], bb[3];
#pragma unroll
    for (int fm = 0; fm < 2; ++fm) af[fm] = *(const bf16x8*)(evT + (fm * 16 + l15) * 264 + ncol);
#pragma unroll
    for (int fe = 0; fe < 3; ++fe) bb[fe] = *(const bf16x8*)(kT + (fe * 16 + l15) * 264 + ncol);
#pragma unroll
    for (int fm = 0; fm < 2; ++fm)
#pragma unroll
      for (int fe = 0; fe < 3; ++fe)
        acc[fm][fe] = __builtin_amdgcn_mfma_f32_16x16x32_bf16(af[fm], bb[fe], acc[fm][fe], 0, 0, 0);
  }
#pragma unroll
  for (int fm = 0; fm < 2; ++fm)
#pragma unroll
    for (int fe = 0; fe < 3; ++fe)
#pragma unroll
      for (int r = 0; r < 4; ++r)
        red[w][(fm * 16 + l4 * 4 + r) * 48 + fe * 16 + l15] = acc[fm][fe][r];
  __syncthreads();
  for (int i = tid; i < 32 * 48; i += 256) {
    const float v = red[0][i] + red[1][i] + red[2][i] + red[3][i];
    const int d = i / 48, e = i - d * 48;
    if (e < 32) atomicAdd(ctx + (long)bh * 1024 + d * 32 + e, v);
    else if (e == 32) atomicAdd(S + bh * 32 + d, v);
  }
}

// ---------------- linear attn out via register softmax + MFMA ----------------
__launch_bounds__(256)
__global__ void lout_kernel(const bf16* __restrict__ qkv, const float* __restrict__ S,
                            const float* __restrict__ ctx, bf16* __restrict__ attn) {
  const int bh = blockIdx.x;
  const int b = bh / 7, h = bh % 7 + 1;
  const int tid = threadIdx.x;
  const int w = tid >> 6, lane = tid & 63;
  const int l15 = lane & 15, l4 = lane >> 4;
  __shared__ bf16 qs[256 * 40];
  __shared__ bf16 C2t[32 * 40];
  const long n0 = (long)blockIdx.y * 256;
  for (int i = tid; i < 1024; i += 256) {
    const int e = i >> 5, d = i & 31;
    C2t[e * 40 + d] = (bf16)(ctx[(long)bh * 1024 + d * 32 + e] / S[bh * 32 + d]);
  }
  const bf16* qp = qkv + ((long)b * 8192 + n0 + tid) * 512 + h * 32;
  bf16x8 qv[4];
#pragma unroll
  for (int c = 0; c < 4; ++c) qv[c] = *(const bf16x8*)(qp + c * 8);
  float qf[32];
#pragma unroll
  for (int c = 0; c < 4; ++c)
#pragma unroll
    for (int j = 0; j < 8; ++j) qf[c * 8 + j] = (float)qv[c][j];
  float m = qf[0];
#pragma unroll
  for (int d = 1; d < 32; ++d) m = fmaxf(m, qf[d]);
  float s = 0.f;
#pragma unroll
  for (int d = 0; d < 32; ++d) { qf[d] = __expf(qf[d] - m); s += qf[d]; }
  const float f = 0.17677669529663687f / s;
#pragma unroll
  for (int c = 0; c < 4; ++c) {
    bf16x8 o;
#pragma unroll
    for (int j = 0; j < 8; ++j) o[j] = (bf16)(qf[c * 8 + j] * f);
    *(bf16x8*)(qs + tid * 40 + c * 8) = o;
  }
  __syncthreads();
  f32x4 acc[4][2] = {};
  bf16x8 bfr[2];
#pragma unroll
  for (int fe = 0; fe < 2; ++fe) bfr[fe] = *(const bf16x8*)(C2t + (fe * 16 + l15) * 40 + l4 * 8);
#pragma unroll
  for (int fm = 0; fm < 4; ++fm) {
    const bf16x8 af = *(const bf16x8*)(qs + (w * 64 + fm * 16 + l15) * 40 + l4 * 8);
#pragma unroll
    for (int fe = 0; fe < 2; ++fe)
      acc[fm][fe] = __builtin_amdgcn_mfma_f32_16x16x32_bf16(af, bfr[fe], acc[fm][fe], 0, 0, 0);
  }
#pragma unroll
  for (int fm = 0; fm < 4; ++fm)
#pragma unroll
    for (int fe = 0; fe < 2; ++fe)
#pragma unroll
      for (int r = 0; r < 4; ++r)
        attn[((long)b * 8192 + n0 + w * 64 + fm * 16 + l4 * 4 + r) * 256 + h * 32 + fe * 16 + l15]
            = (bf16)acc[fm][fe][r];
}

extern "C" void kernel_launch(void* const* d_in, const int* in_sizes, int n_in,
                              void* d_out, int out_size, void* d_ws, size_t ws_size,
                              hipStream_t stream) {
  const float* x     = (const float*)d_in[0];
  const float* n1g   = (const float*)d_in[1];
  const float* n1b   = (const float*)d_in[2];
  const float* Wq    = (const float*)d_in[3];
  const float* Wkv   = (const float*)d_in[4];
  const float* Wproj = (const float*)d_in[5];
  const float* bproj = (const float*)d_in[6];
  const float* n2g   = (const float*)d_in[7];
  const float* n2b   = (const float*)d_in[8];
  const float* W1    = (const float*)d_in[9];
  const float* b1    = (const float*)d_in[10];
  const float* W2    = (const float*)d_in[11];
  const float* b2    = (const float*)d_in[12];
  float* out = (float*)d_out;
  char* ws = (char*)d_ws;

  bf16* wqkv   = (bf16*)(ws + 0);
  bf16* wprojb = (bf16*)(ws + 262144);
  bf16* w1b    = (bf16*)(ws + 393216);
  bf16* w2b    = (bf16*)(ws + 917504);
  float* Sbuf  = (float*)(ws + 1441792);   // 56*32 f32, contiguous with ctx for one memset
  float* ctx   = (float*)(ws + 1448960);   // 56*1024 f32
  bf16* hbuf   = (bf16*)(ws + 1685504);    // 65536x256 bf16 (h1 -> attn -> h2)
  bf16* qkv    = (bf16*)(ws + 35239936);   // 65536x512 bf16
  bf16* hidden = qkv;                      // 65536x1024 bf16 reuses qkv region

  cvt_weights<<<2816, 256, 0, stream>>>(Wq, Wkv, Wproj, W1, W2, wqkv, wprojb, w1b, w2b);
  ln_kernel<<<16384, 256, 0, stream>>>(x, n1g, n1b, hbuf);
  // qkv: [65536x512] = h1 @ WqkvT, K=256
  gemm_bd<0, 64, 512, 256, 2><<<dim3(1024, 1), 512, 0, stream>>>(hbuf, wqkv, qkv, nullptr, nullptr, 512);
  hipMemsetAsync(Sbuf, 0, 7168 + 229376, stream);
  lattn_kernel<<<dim3(128, 8), 256, 0, stream>>>(qkv, hbuf);
  ctx_kernel<<<dim3(56, 32), 256, 0, stream>>>(qkv, ctx, Sbuf);
  lout_kernel<<<dim3(56, 32), 256, 0, stream>>>(qkv, Sbuf, ctx, hbuf);
  // proj + residual: out f32 = attn @ WprojT + bproj + x, K=256
  gemm_bd<1, 64, 256, 256, 2><<<dim3(1024, 1), 512, 0, stream>>>(hbuf, wprojb, out, bproj, x, 256);
  ln_kernel<<<16384, 256, 0, stream>>>(out, n2g, n2b, hbuf);
  // mlp1: hidden bf16 = gelu(h2 @ W1T + b1), K=256, N=1024 in two 512-tiles
  gemm_bd<2, 64, 512, 256, 2><<<dim3(1024, 2), 512, 0, stream>>>(hbuf, w1b, hidden, b1, nullptr, 1024);
  // mlp2 + residual: out f32 += hidden @ W2T + b2, K=1024
  gemm_bd<1, 64, 256, 1024, 4><<<dim3(1024, 1), 512, 0, stream>>>(hidden, w2b, out, b2, out, 256);
}

// Round 5
// 332.406 us; speedup vs baseline: 3.0885x; 1.2130x over previous
//
#include <hip/hip_runtime.h>
#include <hip/hip_bf16.h>

typedef __bf16 bf16;
typedef __bf16 bf16x8 __attribute__((ext_vector_type(8)));
typedef float f32x4 __attribute__((ext_vector_type(4)));

__device__ __forceinline__ void gld16(const void* g, void* l) {
  __builtin_amdgcn_global_load_lds((const __attribute__((address_space(1))) void*)g,
                                   (__attribute__((address_space(3))) void*)l, 16, 0, 0);
}

// ---------------- weight fp32 -> bf16 convert ----------------
__global__ void cvt_weights(const float* __restrict__ wq, const float* __restrict__ wkv,
                            const float* __restrict__ wp, const float* __restrict__ w1,
                            const float* __restrict__ w2,
                            bf16* __restrict__ wqkv, bf16* __restrict__ wpb,
                            bf16* __restrict__ w1b, bf16* __restrict__ w2b) {
  int i = blockIdx.x * 256 + threadIdx.x;
  if (i < 65536) wqkv[i] = (bf16)wq[i];
  else if (i < 131072) wqkv[i] = (bf16)wkv[i - 65536];
  else if (i < 196608) wpb[i - 131072] = (bf16)wp[i - 131072];
  else if (i < 458752) w1b[i - 196608] = (bf16)w1[i - 196608];
  else if (i < 720896) w2b[i - 458752] = (bf16)w2[i - 458752];
}

// ---------------- LayerNorm (wave per row, rows of 256) ----------------
__launch_bounds__(256)
__global__ void ln_kernel(const float* __restrict__ x, const float* __restrict__ g,
                          const float* __restrict__ b, bf16* __restrict__ out) {
  const int row = blockIdx.x * 4 + (threadIdx.x >> 6);
  const int lane = threadIdx.x & 63;
  const float4 v = ((const float4*)(x + (long)row * 256))[lane];
  float s = v.x + v.y + v.z + v.w;
#pragma unroll
  for (int o = 1; o < 64; o <<= 1) s += __shfl_xor(s, o);
  const float mu = s * (1.f / 256.f);
  const float dx = v.x - mu, dy = v.y - mu, dz = v.z - mu, dw = v.w - mu;
  float q = dx * dx + dy * dy + dz * dz + dw * dw;
#pragma unroll
  for (int o = 1; o < 64; o <<= 1) q += __shfl_xor(q, o);
  const float rstd = rsqrtf(q * (1.f / 256.f) + 1e-5f);
  const float4 gg = ((const float4*)g)[lane];
  const float4 bb = ((const float4*)b)[lane];
  union { bf16 h[4]; uint2 u; } pk;
  pk.h[0] = (bf16)(dx * rstd * gg.x + bb.x);
  pk.h[1] = (bf16)(dy * rstd * gg.y + bb.y);
  pk.h[2] = (bf16)(dz * rstd * gg.z + bb.z);
  pk.h[3] = (bf16)(dw * rstd * gg.w + bb.w);
  *(uint2*)(out + (long)row * 256 + lane * 4) = pk.u;
}

// ---------------- persistent-B pipelined GEMM ----------------
// C[65536 x ldC](cols cg*COLS..+COLS) = A[65536 x KK] @ B[ldC x KK]^T  (row slice per block)
// B: entire per-block slice loaded ONCE into VGPRs (no vmem in K-loop).
// A: LDS 3-buffer pipeline, stage issued after barrier, counted vmcnt (never 0).
// Epilogue: LDS bounce -> 16B/lane coalesced stores. EPI 0: bf16; 1: f32 +bias+res; 2: bf16 gelu(+bias).
template <int EPI, int NCG, int NCHUNK, int THREADS, int MSPLIT>
__launch_bounds__(THREADS, (THREADS == 512) ? 4 : 2)
__global__ void gemm_pb(const bf16* __restrict__ A, const bf16* __restrict__ Bw,
                        void* C, const float* __restrict__ bias,
                        const float* res, int ldC) {
  constexpr int WAVES = THREADS / 64;
  constexpr int WR = (THREADS == 512) ? 2 : 1;       // row-groups of waves
  constexpr int WC = WAVES / WR;                     // col-groups of waves
  constexpr int FN = (THREADS == 512) ? 2 : 1;       // col frags per wave
  constexpr int FM = 64 / WR / 16;                   // row frags per wave
  constexpr int COLS = WC * FN * 16;                 // cols per block (128 or 64)
  constexpr int KK = NCHUNK * 128;
  constexpr int ITER = 64 * 128 * 2 / (THREADS * 16);     // gld16 per stage (2 or 4)
  constexpr int TILES = 65536 / MSPLIT / 64;
  constexpr int CHB = 64 * 128 * 2;                  // 16 KB chunk
  constexpr int BSZ = (EPI == 1) ? 64 * COLS * 4 : 64 * COLS * 2;
  constexpr int NST = (EPI == 1) ? 12 : 2;           // vmem ops per thread in epilogue
  constexpr int NBLK = NCG * MSPLIT;
  __shared__ char smem[3 * CHB + BSZ];
  const int tid = threadIdx.x;
  const int w = tid >> 6, lane = tid & 63;
  const int l15 = lane & 15, l4 = lane >> 4;
  const int wrow = w & (WR - 1), wcol = w / WR;
  // bijective XCD swizzle: each XCD gets contiguous strips with all their col-groups
  const int bid = blockIdx.x;
  const int slot = (bid & 7) * (NBLK / 8) + (bid >> 3);
  const int cg = slot % NCG;
  const long strip0 = (long)(slot / NCG) * (65536 / MSPLIT);

  // ---- B slice -> registers (once) ----
  const bf16* Bl = Bw + (long)(cg * COLS + wcol * FN * 16 + l15) * KK + l4 * 8;
  bf16x8 Breg[NCHUNK][4][FN];
#pragma unroll
  for (int c = 0; c < NCHUNK; ++c)
#pragma unroll
    for (int kl = 0; kl < 4; ++kl)
#pragma unroll
      for (int fn = 0; fn < FN; ++fn)
        Breg[c][kl][fn] = *(const bf16x8*)(Bl + (long)fn * 16 * KK + c * 128 + kl * 32);

  float bias_r[FN];
  if constexpr (EPI == 2) {
#pragma unroll
    for (int fn = 0; fn < FN; ++fn)
      bias_r[fn] = bias[cg * COLS + wcol * FN * 16 + fn * 16 + l15];
  }

  auto stage = [&](int m, int c, int buf) {
#pragma unroll
    for (int it = 0; it < ITER; ++it) {
      const int p = it * (THREADS * 16) + tid * 16;
      const int row = p >> 8;                                   // 256B rows (CK=128 bf16)
      const int colb = (p & 255) ^ ((row & 7) << 4);            // inverse swizzle at source
      gld16((const char*)A + ((strip0 + m * 64 + row) * KK + c * 128) * 2 + colb,
            smem + buf * CHB + it * (THREADS * 16) + w * 1024);
    }
  };

  f32x4 acc[FM][FN] = {};
  stage(0, 0, 0);
  stage(0, 1, 1);

  for (int m = 0; m < TILES; ++m) {
#pragma unroll
    for (int c = 0; c < NCHUNK; ++c) {
      const int s = m * NCHUNK + c;
      if (m == 0 || c >= 2) {
        asm volatile("s_waitcnt vmcnt(%0)" ::"i"(ITER) : "memory");
      } else {
        asm volatile("s_waitcnt vmcnt(%0)" ::"i"(ITER + NST) : "memory");
      }
      __syncthreads();
      {  // issue stage for step s+2 (after barrier: all readers of its buffer are done)
        int c2 = c + 2, m2 = m;
        if (c2 >= NCHUNK) { c2 -= NCHUNK; ++m2; }
        if (m2 < TILES) stage(m2, c2, (s + 2) % 3);
      }
      const char* Ab = smem + (s % 3) * CHB;
#pragma unroll
      for (int kl = 0; kl < 4; ++kl) {
        bf16x8 af[FM];
#pragma unroll
        for (int fm = 0; fm < FM; ++fm) {
          const int arow = wrow * (64 / WR) + fm * 16 + l15;
          af[fm] = *(const bf16x8*)(Ab + arow * 256 + ((kl * 64 + l4 * 16) ^ ((l15 & 7) << 4)));
        }
#pragma unroll
        for (int fm = 0; fm < FM; ++fm)
#pragma unroll
          for (int fn = 0; fn < FN; ++fn)
            acc[fm][fn] = __builtin_amdgcn_mfma_f32_16x16x32_bf16(af[fm], Breg[c][kl][fn],
                                                                  acc[fm][fn], 0, 0, 0);
      }
      if (c == NCHUNK - 1) {
        // ---- epilogue: acc -> LDS bounce -> coalesced 16B stores ----
        if constexpr (EPI == 1) {
          float* fb = (float*)(smem + 3 * CHB);
#pragma unroll
          for (int fm = 0; fm < FM; ++fm)
#pragma unroll
            for (int fn = 0; fn < FN; ++fn)
#pragma unroll
              for (int r = 0; r < 4; ++r)
                fb[(wrow * (64 / WR) + fm * 16 + l4 * 4 + r) * COLS +
                   wcol * FN * 16 + fn * 16 + l15] = acc[fm][fn][r];
          __syncthreads();
#pragma unroll
          for (int it = 0; it < 64 * COLS * 4 / (THREADS * 16); ++it) {
            const int off = it * (THREADS * 16) + tid * 16;
            const int row = off / (COLS * 4);
            const int colb = off % (COLS * 4);
            const long gb = ((strip0 + m * 64 + row) * ldC + cg * COLS) * 4 + colb;
            float4 v = *(const float4*)(smem + 3 * CHB + off);
            const float4 rr = *(const float4*)((const char*)res + gb);
            const float4 bv = *(const float4*)((const char*)bias + cg * COLS * 4 + colb);
            v.x += rr.x + bv.x; v.y += rr.y + bv.y;
            v.z += rr.z + bv.z; v.w += rr.w + bv.w;
            *(float4*)((char*)C + gb) = v;
          }
        } else {
          bf16* bb = (bf16*)(smem + 3 * CHB);
#pragma unroll
          for (int fm = 0; fm < FM; ++fm)
#pragma unroll
            for (int fn = 0; fn < FN; ++fn)
#pragma unroll
              for (int r = 0; r < 4; ++r) {
                float v = acc[fm][fn][r];
                if constexpr (EPI == 2) {
                  v += bias_r[fn];
                  v = 0.5f * v * (1.f + erff(v * 0.70710678118654752f));
                }
                bb[(wrow * (64 / WR) + fm * 16 + l4 * 4 + r) * COLS +
                   wcol * FN * 16 + fn * 16 + l15] = (bf16)v;
              }
          __syncthreads();
#pragma unroll
          for (int it = 0; it < 64 * COLS * 2 / (THREADS * 16); ++it) {
            const int off = it * (THREADS * 16) + tid * 16;
            const int row = off / (COLS * 2);
            const int colb = off % (COLS * 2);
            *(uint4*)((char*)C + ((strip0 + m * 64 + row) * ldC + cg * COLS) * 2 + colb) =
                *(const uint4*)(smem + 3 * CHB + off);
          }
        }
#pragma unroll
        for (int fm = 0; fm < FM; ++fm)
#pragma unroll
          for (int fn = 0; fn < FN; ++fn)
            acc[fm][fn] = f32x4{0.f, 0.f, 0.f, 0.f};
      }
    }
  }
}

// ---------------- local window attention (head 0), one block per (window, batch) ----------------
__launch_bounds__(256)
__global__ void lattn_kernel(const bf16* __restrict__ qkv, bf16* __restrict__ attn) {
  const int j = blockIdx.x, b = blockIdx.y;
  const int tid = threadIdx.x, w = tid >> 6, lane = tid & 63;
  __shared__ bf16 Qs[64 * 40];
  __shared__ bf16 Ks[192 * 40];
  __shared__ bf16 Kt[32 * 200];
  __shared__ bf16 Ps[4][16 * 200];
  const float scale = 0.17677669529663687f;
  const long base = (long)b * 8192 + (long)j * 64;
  for (int i = tid; i < 64 * 32; i += 256) {
    const int r = i >> 5, d = i & 31;
    Qs[r * 40 + d] = (bf16)((float)qkv[(base + r) * 512 + d] * scale);
  }
  for (int i = tid; i < 192 * 32; i += 256) {
    const int c = i >> 5, d = i & 31;
    const long tc = (long)j * 64 - 64 + c;
    float kv = 0.f;
    if (tc >= 0 && tc < 8192) kv = (float)qkv[((long)b * 8192 + tc) * 512 + 256 + d];
    const bf16 kb = (bf16)kv;
    Ks[c * 40 + d] = kb;
    Kt[d * 200 + c] = kb;
  }
  __syncthreads();
  const int l15 = lane & 15, l4 = lane >> 4;
  const bf16x8 aq = *(const bf16x8*)(Qs + (w * 16 + l15) * 40 + l4 * 8);
  const f32x4 zz = {0.f, 0.f, 0.f, 0.f};
  f32x4 S[12];
#pragma unroll
  for (int fn = 0; fn < 12; ++fn) {
    const bf16x8 bk = *(const bf16x8*)(Ks + (fn * 16 + l15) * 40 + l4 * 8);
    S[fn] = __builtin_amdgcn_mfma_f32_16x16x32_bf16(aq, bk, zz, 0, 0, 0);
  }
#pragma unroll
  for (int fn = 0; fn < 12; ++fn) {
    const long tc = (long)j * 64 - 64 + fn * 16 + l15;
    if (tc < 0 || tc >= 8192) { S[fn][0] = -1e9f; S[fn][1] = -1e9f; S[fn][2] = -1e9f; S[fn][3] = -1e9f; }
  }
  float sinv[4];
#pragma unroll
  for (int r = 0; r < 4; ++r) {
    float m = -1e30f;
#pragma unroll
    for (int fn = 0; fn < 12; ++fn) m = fmaxf(m, S[fn][r]);
#pragma unroll
    for (int o = 1; o < 16; o <<= 1) m = fmaxf(m, __shfl_xor(m, o));
    float s = 0.f;
#pragma unroll
    for (int fn = 0; fn < 12; ++fn) { const float e = __expf(S[fn][r] - m); S[fn][r] = e; s += e; }
#pragma unroll
    for (int o = 1; o < 16; o <<= 1) s += __shfl_xor(s, o);
    sinv[r] = 1.f / s;
  }
#pragma unroll
  for (int fn = 0; fn < 12; ++fn)
#pragma unroll
    for (int r = 0; r < 4; ++r)
      Ps[w][(l4 * 4 + r) * 200 + fn * 16 + l15] = (bf16)(S[fn][r] * sinv[r]);
  __syncthreads();
  f32x4 O[2] = {};
#pragma unroll
  for (int ks = 0; ks < 6; ++ks) {
    const bf16x8 ap = *(const bf16x8*)(Ps[w] + l15 * 200 + ks * 32 + l4 * 8);
#pragma unroll
    for (int fe = 0; fe < 2; ++fe) {
      const bf16x8 bv = *(const bf16x8*)(Kt + (fe * 16 + l15) * 200 + ks * 32 + l4 * 8);
      O[fe] = __builtin_amdgcn_mfma_f32_16x16x32_bf16(ap, bv, O[fe], 0, 0, 0);
    }
  }
#pragma unroll
  for (int fe = 0; fe < 2; ++fe)
#pragma unroll
    for (int r = 0; r < 4; ++r)
      attn[(base + w * 16 + l4 * 4 + r) * 256 + fe * 16 + l15] = (bf16)O[fe][r];
}

// ---------------- linear attn ctx via MFMA (S via ones-row) ----------------
__launch_bounds__(256)
__global__ void ctx_kernel(const bf16* __restrict__ qkv, float* __restrict__ ctx,
                           float* __restrict__ S) {
  const int bh = blockIdx.x;
  const int b = bh / 7, h = bh % 7 + 1;
  const int tid = threadIdx.x;
  const int w = tid >> 6, lane = tid & 63;
  const int l15 = lane & 15, l4 = lane >> 4;
  __shared__ bf16 evT[32 * 264];
  __shared__ bf16 kT[48 * 264];
  __shared__ float red[4][32 * 48];
  const long n0 = (long)blockIdx.y * 256;
  const bf16* kp = qkv + ((long)b * 8192 + n0 + tid) * 512 + 256 + h * 32;
  bf16x8 kv[4];
#pragma unroll
  for (int c = 0; c < 4; ++c) kv[c] = *(const bf16x8*)(kp + c * 8);
#pragma unroll
  for (int i = 0; i < 16; ++i)
    kT[(32 + i) * 264 + tid] = (i == 0) ? (bf16)1.0f : (bf16)0.0f;
#pragma unroll
  for (int c = 0; c < 4; ++c)
#pragma unroll
    for (int j = 0; j < 8; ++j) {
      const int d = c * 8 + j;
      evT[d * 264 + tid] = (bf16)__expf((float)kv[c][j]);
      kT[d * 264 + tid] = kv[c][j];
    }
  __syncthreads();
  f32x4 acc[2][3] = {};
#pragma unroll
  for (int ks = 0; ks < 2; ++ks) {
    const int ncol = w * 64 + ks * 32 + l4 * 8;
    bf16x8 af[2], bb[3];
#pragma unroll
    for (int fm = 0; fm < 2; ++fm) af[fm] = *(const bf16x8*)(evT + (fm * 16 + l15) * 264 + ncol);
#pragma unroll
    for (int fe = 0; fe < 3; ++fe) bb[fe] = *(const bf16x8*)(kT + (fe * 16 + l15) * 264 + ncol);
#pragma unroll
    for (int fm = 0; fm < 2; ++fm)
#pragma unroll
      for (int fe = 0; fe < 3; ++fe)
        acc[fm][fe] = __builtin_amdgcn_mfma_f32_16x16x32_bf16(af[fm], bb[fe], acc[fm][fe], 0, 0, 0);
  }
#pragma unroll
  for (int fm = 0; fm < 2; ++fm)
#pragma unroll
    for (int fe = 0; fe < 3; ++fe)
#pragma unroll
      for (int r = 0; r < 4; ++r)
        red[w][(fm * 16 + l4 * 4 + r) * 48 + fe * 16 + l15] = acc[fm][fe][r];
  __syncthreads();
  for (int i = tid; i < 32 * 48; i += 256) {
    const float v = red[0][i] + red[1][i] + red[2][i] + red[3][i];
    const int d = i / 48, e = i - d * 48;
    if (e < 32) atomicAdd(ctx + (long)bh * 1024 + d * 32 + e, v);
    else if (e == 32) atomicAdd(S + bh * 32 + d, v);
  }
}

// ---------------- linear attn out via register softmax + MFMA ----------------
__launch_bounds__(256)
__global__ void lout_kernel(const bf16* __restrict__ qkv, const float* __restrict__ S,
                            const float* __restrict__ ctx, bf16* __restrict__ attn) {
  const int bh = blockIdx.x;
  const int b = bh / 7, h = bh % 7 + 1;
  const int tid = threadIdx.x;
  const int w = tid >> 6, lane = tid & 63;
  const int l15 = lane & 15, l4 = lane >> 4;
  __shared__ bf16 qs[256 * 40];
  __shared__ bf16 C2t[32 * 40];
  const long n0 = (long)blockIdx.y * 256;
  for (int i = tid; i < 1024; i += 256) {
    const int e = i >> 5, d = i & 31;
    C2t[e * 40 + d] = (bf16)(ctx[(long)bh * 1024 + d * 32 + e] / S[bh * 32 + d]);
  }
  const bf16* qp = qkv + ((long)b * 8192 + n0 + tid) * 512 + h * 32;
  bf16x8 qv[4];
#pragma unroll
  for (int c = 0; c < 4; ++c) qv[c] = *(const bf16x8*)(qp + c * 8);
  float qf[32];
#pragma unroll
  for (int c = 0; c < 4; ++c)
#pragma unroll
    for (int j = 0; j < 8; ++j) qf[c * 8 + j] = (float)qv[c][j];
  float m = qf[0];
#pragma unroll
  for (int d = 1; d < 32; ++d) m = fmaxf(m, qf[d]);
  float s = 0.f;
#pragma unroll
  for (int d = 0; d < 32; ++d) { qf[d] = __expf(qf[d] - m); s += qf[d]; }
  const float f = 0.17677669529663687f / s;
#pragma unroll
  for (int c = 0; c < 4; ++c) {
    bf16x8 o;
#pragma unroll
    for (int j = 0; j < 8; ++j) o[j] = (bf16)(qf[c * 8 + j] * f);
    *(bf16x8*)(qs + tid * 40 + c * 8) = o;
  }
  __syncthreads();
  f32x4 acc[4][2] = {};
  bf16x8 bfr[2];
#pragma unroll
  for (int fe = 0; fe < 2; ++fe) bfr[fe] = *(const bf16x8*)(C2t + (fe * 16 + l15) * 40 + l4 * 8);
#pragma unroll
  for (int fm = 0; fm < 4; ++fm) {
    const bf16x8 af = *(const bf16x8*)(qs + (w * 64 + fm * 16 + l15) * 40 + l4 * 8);
#pragma unroll
    for (int fe = 0; fe < 2; ++fe)
      acc[fm][fe] = __builtin_amdgcn_mfma_f32_16x16x32_bf16(af, bfr[fe], acc[fm][fe], 0, 0, 0);
  }
#pragma unroll
  for (int fm = 0; fm < 4; ++fm)
#pragma unroll
    for (int fe = 0; fe < 2; ++fe)
#pragma unroll
      for (int r = 0; r < 4; ++r)
        attn[((long)b * 8192 + n0 + w * 64 + fm * 16 + l4 * 4 + r) * 256 + h * 32 + fe * 16 + l15]
            = (bf16)acc[fm][fe][r];
}

extern "C" void kernel_launch(void* const* d_in, const int* in_sizes, int n_in,
                              void* d_out, int out_size, void* d_ws, size_t ws_size,
                              hipStream_t stream) {
  const float* x     = (const float*)d_in[0];
  const float* n1g   = (const float*)d_in[1];
  const float* n1b   = (const float*)d_in[2];
  const float* Wq    = (const float*)d_in[3];
  const float* Wkv   = (const float*)d_in[4];
  const float* Wproj = (const float*)d_in[5];
  const float* bproj = (const float*)d_in[6];
  const float* n2g   = (const float*)d_in[7];
  const float* n2b   = (const float*)d_in[8];
  const float* W1    = (const float*)d_in[9];
  const float* b1    = (const float*)d_in[10];
  const float* W2    = (const float*)d_in[11];
  const float* b2    = (const float*)d_in[12];
  float* out = (float*)d_out;
  char* ws = (char*)d_ws;

  bf16* wqkv   = (bf16*)(ws + 0);
  bf16* wprojb = (bf16*)(ws + 262144);
  bf16* w1b    = (bf16*)(ws + 393216);
  bf16* w2b    = (bf16*)(ws + 917504);
  float* Sbuf  = (float*)(ws + 1441792);   // 56*32 f32, contiguous with ctx for one memset
  float* ctx   = (float*)(ws + 1448960);   // 56*1024 f32
  bf16* hbuf   = (bf16*)(ws + 1685504);    // 65536x256 bf16 (h1 -> attn -> h2)
  bf16* qkv    = (bf16*)(ws + 35239936);   // 65536x512 bf16
  bf16* hidden = qkv;                      // 65536x1024 bf16 reuses qkv region

  cvt_weights<<<2816, 256, 0, stream>>>(Wq, Wkv, Wproj, W1, W2, wqkv, wprojb, w1b, w2b);
  ln_kernel<<<16384, 256, 0, stream>>>(x, n1g, n1b, hbuf);
  // qkv: [65536x512] = h1 @ WqkvT, K=256. NCG=4, MSPLIT=128 -> 512 blocks
  gemm_pb<0, 4, 2, 512, 128><<<512, 512, 0, stream>>>(hbuf, wqkv, qkv, nullptr, nullptr, 512);
  hipMemsetAsync(Sbuf, 0, 7168 + 229376, stream);
  lattn_kernel<<<dim3(128, 8), 256, 0, stream>>>(qkv, hbuf);
  ctx_kernel<<<dim3(56, 32), 256, 0, stream>>>(qkv, ctx, Sbuf);
  lout_kernel<<<dim3(56, 32), 256, 0, stream>>>(qkv, Sbuf, ctx, hbuf);
  // proj + residual: out f32 = attn @ WprojT + bproj + x. NCG=2, MSPLIT=256 -> 512 blocks
  gemm_pb<1, 2, 2, 512, 256><<<512, 512, 0, stream>>>(hbuf, wprojb, out, bproj, x, 256);
  ln_kernel<<<16384, 256, 0, stream>>>(out, n2g, n2b, hbuf);
  // mlp1: hidden bf16 = gelu(h2 @ W1T + b1). NCG=8, MSPLIT=64 -> 512 blocks
  gemm_pb<2, 8, 2, 512, 64><<<512, 512, 0, stream>>>(hbuf, w1b, hidden, b1, nullptr, 1024);
  // mlp2 + residual: out f32 += hidden @ W2T + b2, K=1024. 256-thr cfg, NCG=4, MSPLIT=256 -> 1024 blocks
  gemm_pb<1, 4, 8, 256, 256><<<1024, 256, 0, stream>>>(hidden, w2b, out, b2, out, 256);
}